// Round 3
// baseline (350.151 us; speedup 1.0000x reference)
//
#include <hip/hip_runtime.h>

// BinaryConnectNet forward.
// R12: k4a reverted to the proven R9/R1 2-buffer structure (ring-3 experiment
// showed drain wasn't the stall: MfmaUtil flat at 1 blk/CU; concurrency wins).
// New: K split 4-way (kh=4, grid 1024) behind a ws-size guard -> 512 queued
// blocks backfill CUs at random phases (de-lockstep + tail smoothing); exact
// (i32 limb bound 4*64*4096 << 2^31; 4-plane double sum associative-exact).
// kprep2 fused into k1 block 0 (one fewer launch). k3 keeps R10's 4-blk/CU
// overlay + async16 staging + setprio (independent-block regime).

__device__ __forceinline__ int fsign(float v)  { return (v > 0.f) - (v < 0.f); }
__device__ __forceinline__ int dsign(double v) { return (v > 0.0) - (v < 0.0); }

typedef int v4i __attribute__((ext_vector_type(4)));

__device__ __forceinline__ void async16(const signed char* g, signed char* l) {
    __builtin_amdgcn_global_load_lds(
        (const __attribute__((address_space(1))) void*)g,
        (__attribute__((address_space(3))) void*)l, 16, 0, 0);
}

// -------- Kernel 1: conv1 dw(3x3,g=3) + pw(1x1 3->128) + sign + maxpool2
// -> pooled1T [n][y16][x16][c128] int8. o-loop via 16-entry pattern table.
// Block 0 additionally performs the conv2-pw prep (former kprep2).
__global__ void k1_conv1(const float* __restrict__ x,
                         const float* __restrict__ w1dw, const float* __restrict__ b1dw,
                         const float* __restrict__ w1pw, const float* __restrict__ b1pw,
                         const float* __restrict__ w2pw, const float* __restrict__ b2pw,
                         signed char* __restrict__ pooled1T,
                         signed char* __restrict__ w2s, int* __restrict__ b2adj)
{
    __shared__ float sdw[27], sbdw[3];
    __shared__ unsigned char spidx[128];
    int t = threadIdx.x;
    if (t < 27) sdw[t] = (float)fsign(w1dw[t]);
    if (t < 3)  sbdw[t] = (float)fsign(b1dw[t]);
    if (t < 128) {
        int b0 = w1pw[t * 3 + 0] > 0.f;
        int b1 = w1pw[t * 3 + 1] > 0.f;
        int b2 = w1pw[t * 3 + 2] > 0.f;
        int b3 = b1pw[t] > 0.f;
        spidx[t] = (unsigned char)(b0 | (b1 << 1) | (b2 << 2) | (b3 << 3));
    }
    __syncthreads();

    int g  = blockIdx.x * 256 + t;
    int px = g & 15, py = (g >> 4) & 15, n = g >> 8;

    double h[3][4];
    const float* xb = x + (size_t)n * 3 * 1024;
    #pragma unroll
    for (int c = 0; c < 3; c++) {
        const float* xc = xb + c * 1024;
        #pragma unroll
        for (int dy = 0; dy < 2; dy++)
        #pragma unroll
        for (int dx = 0; dx < 2; dx++) {
            int y = 2 * py + dy, xx = 2 * px + dx;
            double acc = (double)sbdw[c];
            #pragma unroll
            for (int ky = 0; ky < 3; ky++) {
                int yy = y + ky - 1;
                if (yy < 0 || yy > 31) continue;
                #pragma unroll
                for (int kx = 0; kx < 3; kx++) {
                    int xxx = xx + kx - 1;
                    if (xxx < 0 || xxx > 31) continue;
                    acc += (double)sdw[c * 9 + ky * 3 + kx] * (double)xc[yy * 32 + xxx];
                }
            }
            h[c][dy * 2 + dx] = acc;
        }
    }

    double tv[4][4];
    #pragma unroll
    for (int q = 0; q < 4; q++) {
        double u = h[0][q] + h[1][q];
        double v = h[0][q] - h[1][q];
        tv[0][q] = v - h[2][q];
        tv[1][q] = u - h[2][q];
        tv[2][q] = v + h[2][q];
        tv[3][q] = u + h[2][q];
    }
    int mpack = 0;
    #pragma unroll
    for (int bp = 0; bp < 4; bp++) {
        int mxP = -2, mnP = 2, mxM = -2, mnM = 2;
        #pragma unroll
        for (int q = 0; q < 4; q++) {
            int sP = dsign(tv[bp][q] + 1.0);
            int sM = dsign(tv[bp][q] - 1.0);
            mxP = max(mxP, sP); mnP = min(mnP, sP);
            mxM = max(mxM, sM); mnM = min(mnM, sM);
        }
        int pat1 = 1 | (bp << 1);
        int pat0 = (~pat1) & 7;
        mpack |= (mxP + 1)   << (2 * (pat1 | 8));
        mpack |= (mxM + 1)   << (2 * pat1);
        mpack |= ((-mnM) + 1) << (2 * (pat0 | 8));
        mpack |= ((-mnP) + 1) << (2 * pat0);
    }

    signed char* outb = pooled1T + (size_t)n * 32768 + (py * 16 + px) * 128;
    const int* pint = (const int*)spidx;
    for (int ob = 0; ob < 32; ob++) {
        int pw = pint[ob];
        int cur = 0;
        #pragma unroll
        for (int e = 0; e < 4; e++) {
            int pi = (pw >> (8 * e)) & 15;
            int mv = ((mpack >> (pi * 2)) & 3) - 1;
            cur |= (mv & 0xff) << (8 * e);
        }
        *(int*)(outb + ob * 4) = cur;
    }

    // Fused former kprep2 (block 0 only): w2s sign matrix + b2adj.
    if (blockIdx.x == 0) {
        int o = t;   // 256 threads -> 256 outputs
        int rs = 0;
        for (int cq = 0; cq < 32; cq++) {
            float4 w = *(const float4*)(w2pw + (size_t)o * 128 + cq * 4);
            int s0 = fsign(w.x), s1 = fsign(w.y), s2 = fsign(w.z), s3 = fsign(w.w);
            rs += s0 + s1 + s2 + s3;
            int pk = (s0 & 0xff) | ((s1 & 0xff) << 8) | ((s2 & 0xff) << 16) | ((s3 & 0xff) << 24);
            *(int*)(w2s + (size_t)o * 128 + cq * 4) = pk;
        }
        b2adj[o] = fsign(b2pw[o]) - 32 * rs;
    }
}

// -------- Kernel 3 (fused): depthwise conv2 + pointwise MFMA GEMM + sign + maxpool
// LDS 38912 B -> 4 blocks/CU co-resident.
__global__ __launch_bounds__(256, 4) void k3_fused(
    const signed char* __restrict__ pooled1T,
    const float* __restrict__ w2dw, const float* __restrict__ b2dw,
    const signed char* __restrict__ w2s, const int* __restrict__ b2adj,
    signed char* __restrict__ hT2)
{
    __shared__ __align__(16) signed char Ps[32768];
    // Phase A (staging + dw conv): sw4[1152] + sdb2[128].
    // Phase B (oc loop, after the first post-MFMA barrier): Os[64*80].
    __shared__ __align__(16) signed char Uni[5120];
    __shared__ int sb2adj[256];

    signed char* sw4  = Uni;
    signed char* sdb2 = Uni + 1152;
    signed char* Os   = Uni;

    int t = threadIdx.x, l = t & 63, wid = t >> 6;
    int n = blockIdx.x;
    const signed char* pb = pooled1T + (size_t)n * 32768;

    // Ps staging: XOR swizzle is an involution, so apply it on the GLOBAL
    // source address and keep the LDS destination lane-linear.
    #pragma unroll
    for (int it = 0; it < 8; it++) {
        int off = it * 4096 + t * 16;
        int p = off >> 7, seg = (off >> 4) & 7;
        async16(pb + p * 128 + ((seg ^ (p & 7)) * 16), &Ps[off]);
    }
    for (int i = t; i < 1152; i += 256) {
        int c = i & 127, tap = i >> 7;
        sw4[tap * 128 + c] = (signed char)fsign(w2dw[c * 9 + tap]);
    }
    if (t < 128) sdb2[t] = (signed char)(fsign(b2dw[t]) + 1);
    if (t < 256) sb2adj[t] = b2adj[t];
    __syncthreads();

    int frow = l & 15;

    v4i af[4][2];
    #pragma unroll
    for (int ks = 0; ks < 2; ks++) {
        int c0 = ks * 64 + (l >> 4) * 16;
        int cc = c0 >> 4;
        int4 w4[9];
        #pragma unroll
        for (int tap = 0; tap < 9; tap++)
            w4[tap] = *(const int4*)&sw4[tap * 128 + c0];
        int4 sdbv = *(const int4*)&sdb2[c0];

        #pragma unroll
        for (int i = 0; i < 4; i++) {
            int r = (wid * 4 + i) * 16 + frow;
            int py = r >> 5, px2 = (r >> 2) & 7, dy = (r >> 1) & 1, dx = r & 1;
            int y = 2 * py + dy, x = 2 * px2 + dx;
            int4 cnt = (int4){0, 0, 0, 0};
            #pragma unroll
            for (int ky = 0; ky < 3; ky++) {
                int yy = y + ky - 1;
                int yc = min(max(yy, 0), 15);
                #pragma unroll
                for (int kx = 0; kx < 3; kx++) {
                    int xx2 = x + kx - 1;
                    int xc = min(max(xx2, 0), 15);
                    int inb = ((yy == yc) && (xx2 == xc)) ? 0x01010101 : 0;
                    int p = yc * 16 + xc;
                    int4 v = *(const int4*)&Ps[p * 128 + ((cc ^ (p & 7)) * 16)];
                    int4 w = w4[ky * 3 + kx];
                    cnt.x += ((v.x ^ w.x) >> 1) & inb;
                    cnt.y += ((v.y ^ w.y) >> 1) & inb;
                    cnt.z += ((v.z ^ w.z) >> 1) & inb;
                    cnt.w += ((v.w ^ w.w) >> 1) & inb;
                }
            }
            int valid = (1 + (y > 0) + (y < 15)) * (1 + (x > 0) + (x < 15));
            int mb = (valid + 31) * 0x01010101;
            int4 u;
            u.x = sdbv.x + mb - (cnt.x + cnt.x);
            u.y = sdbv.y + mb - (cnt.y + cnt.y);
            u.z = sdbv.z + mb - (cnt.z + cnt.z);
            u.w = sdbv.w + mb - (cnt.w + cnt.w);
            af[i][ks] = (v4i){u.x, u.y, u.z, u.w};
        }
    }

    for (int oc = 0; oc < 4; oc++) {
        v4i acc[4][4];
        #pragma unroll
        for (int i = 0; i < 4; i++)
            #pragma unroll
            for (int jt = 0; jt < 4; jt++) acc[i][jt] = (v4i){0, 0, 0, 0};

        #pragma unroll
        for (int ks = 0; ks < 2; ks++) {
            v4i bf[4];
            #pragma unroll
            for (int jt = 0; jt < 4; jt++)
                bf[jt] = *(const v4i*)(w2s + (size_t)(oc * 64 + jt * 16 + frow) * 128
                                       + ks * 64 + (l >> 4) * 16);
            __builtin_amdgcn_s_setprio(1);
            #pragma unroll
            for (int i = 0; i < 4; i++)
                #pragma unroll
                for (int jt = 0; jt < 4; jt++)
                    acc[i][jt] = __builtin_amdgcn_mfma_i32_16x16x64_i8(af[i][ks], bf[jt], acc[i][jt], 0, 0, 0);
            __builtin_amdgcn_s_setprio(0);
        }

        __syncthreads();
        // From here Uni is the Os staging buffer (sw4/sdb2 dead).
        #pragma unroll
        for (int jt = 0; jt < 4; jt++) {
            int o_l = jt * 16 + frow;
            int bia = sb2adj[oc * 64 + o_l];
            #pragma unroll
            for (int i = 0; i < 4; i++) {
                int mx = -2;
                #pragma unroll
                for (int rr = 0; rr < 4; rr++) {
                    int p = acc[i][jt][rr] + bia;
                    int s = (p > 0) - (p < 0);
                    mx = s > mx ? s : mx;
                }
                int pp = (wid * 4 + i) * 4 + (l >> 4);
                Os[o_l * 80 + pp] = (signed char)mx;
            }
        }
        __syncthreads();
        *(int4*)&hT2[(size_t)n * 16384 + oc * 4096 + t * 16]
            = *(const int4*)&Os[(t >> 2) * 80 + (t & 3) * 16];
    }
}

// -------- Prep: fc1_w -> 4 signed radix-128 int8 limbs on 2^-32 grid (exact).
__global__ void kprep(const float* __restrict__ fc1w, signed char* __restrict__ BL)
{
    int t = threadIdx.x;
    int b = blockIdx.x;
    int j = b >> 4, kb = b & 15;
    int k0 = kb * 1024 + t * 4;
    float4 w = *(const float4*)(fc1w + (size_t)j * 16384 + k0);
    float we[4] = {w.x, w.y, w.z, w.w};
    int out[4] = {0, 0, 0, 0};
    #pragma unroll
    for (int e = 0; e < 4; e++) {
        int q = (int)rint((double)we[e] * 4294967296.0);
        q = min(max(q, -266338304), 266338304);
        int d0 = ((q + 64) & 127) - 64; q = (q - d0) >> 7;
        int d1 = ((q + 64) & 127) - 64; q = (q - d1) >> 7;
        int d2 = ((q + 64) & 127) - 64; q = (q - d2) >> 7;
        int d3 = q;
        out[0] |= (d0 & 0xff) << (8 * e);
        out[1] |= (d1 & 0xff) << (8 * e);
        out[2] |= (d2 & 0xff) << (8 * e);
        out[3] |= (d3 & 0xff) << (8 * e);
    }
    #pragma unroll
    for (int m = 0; m < 4; m++)
        *(int*)(BL + (size_t)(j * 4 + m) * 16384 + k0) = out[m];
}

// -------- Kernel 4a: fc1 GEMM, K-split grid (KBLK per block) + K-phase waves.
// R12: proven R9 2-buffer structure, templated on KBLK so kh=4 (backfill
// de-lockstep) and kh=2 paths share code with literal loop bounds.
template<int KBLK>
__global__ __launch_bounds__(512, 4) void k4a_fc1(
    const signed char* __restrict__ hT2, const signed char* __restrict__ BL,
    double* __restrict__ Pd)
{
    constexpr int ITERS = KBLK / 128;
    __shared__ __align__(16) signed char smem[65536];
    int t = threadIdx.x, l = t & 63, wid = t >> 6;
    int nb0 = blockIdx.y * 128, jb0 = blockIdx.x * 128;
    int kh = blockIdx.z, k0 = kh * KBLK;
    int ksw = wid >> 2;                       // K-phase of this wave
    int wn0 = ((wid >> 1) & 1) * 64, wj0 = (wid & 1) * 64;

    int srow = l >> 3;
    int sseg = ((l & 7) ^ srow) * 16;
    const signed char* gA = hT2 + (size_t)(nb0 + wid * 16 + srow) * 16384 + k0 + sseg;
    const signed char* gB = BL  + (size_t)(jb0 + wid * 16 + srow) * 16384 + k0 + sseg;

    v4i acc[4][4];
    #pragma unroll
    for (int i = 0; i < 4; i++)
        #pragma unroll
        for (int q = 0; q < 4; q++) acc[i][q] = (v4i){0, 0, 0, 0};

    {
        signed char* As = smem;
        signed char* Bs = smem + 16384;
        #pragma unroll
        for (int c = 0; c < 2; c++) {
            async16(gA + (size_t)c * 8 * 16384, As + (wid * 16 + c * 8) * 128);
            async16(gB + (size_t)c * 8 * 16384, Bs + (wid * 16 + c * 8) * 128);
        }
    }

    int sw = (((ksw * 4) + (l >> 4)) ^ (l & 7)) * 16;

    for (int it = 0; it < ITERS; it++) {
        __syncthreads();
        if (it + 1 < ITERS) {
            int kt = (it + 1) * 128;
            signed char* As = smem + ((it + 1) & 1) * 32768;
            signed char* Bs = As + 16384;
            #pragma unroll
            for (int c = 0; c < 2; c++) {
                async16(gA + (size_t)c * 8 * 16384 + kt, As + (wid * 16 + c * 8) * 128);
                async16(gB + (size_t)c * 8 * 16384 + kt, Bs + (wid * 16 + c * 8) * 128);
            }
        }
        const signed char* As = smem + (it & 1) * 32768;
        const signed char* Bs = As + 16384;
        v4i af[4], bf[4];
        #pragma unroll
        for (int i = 0; i < 4; i++)
            af[i] = *(const v4i*)&As[(wn0 + i * 16 + (l & 15)) * 128 + sw];
        #pragma unroll
        for (int q = 0; q < 4; q++)
            bf[q] = *(const v4i*)&Bs[(wj0 + q * 16 + (l & 15)) * 128 + sw];
        #pragma unroll
        for (int i = 0; i < 4; i++)
            #pragma unroll
            for (int q = 0; q < 4; q++)
                acc[i][q] = __builtin_amdgcn_mfma_i32_16x16x64_i8(af[i], bf[q], acc[i][q], 0, 0, 0);
    }

    __syncthreads();
    int* S = (int*)smem;    // [128 n][128 jm]
    if (ksw == 0) {
        #pragma unroll
        for (int i = 0; i < 4; i++)
            #pragma unroll
            for (int q = 0; q < 4; q++)
                #pragma unroll
                for (int rr = 0; rr < 4; rr++) {
                    int n_l  = wn0 + i * 16 + (l >> 4) * 4 + rr;
                    int jm_l = wj0 + q * 16 + (l & 15);
                    S[n_l * 128 + jm_l] = acc[i][q][rr];
                }
    }
    __syncthreads();
    if (ksw == 1) {
        #pragma unroll
        for (int i = 0; i < 4; i++)
            #pragma unroll
            for (int q = 0; q < 4; q++)
                #pragma unroll
                for (int rr = 0; rr < 4; rr++) {
                    int n_l  = wn0 + i * 16 + (l >> 4) * 4 + rr;
                    int jm_l = wj0 + q * 16 + (l & 15);
                    S[n_l * 128 + jm_l] += acc[i][q][rr];
                }
    }
    __syncthreads();

    #pragma unroll
    for (int e = 0; e < 8; e++) {
        int idx = t * 8 + e;                 // 4096 = 128 n x 32 j
        int n_l = idx >> 5, j_l = idx & 31;
        int4 s = *(const int4*)&S[n_l * 128 + j_l * 4];
        double val = (double)s.x + 128.0 * (double)s.y
                   + 16384.0 * (double)s.z + 2097152.0 * (double)s.w;
        Pd[(size_t)kh * 1048576 + (size_t)(nb0 + n_l) * 1024 + blockIdx.x * 32 + j_l] = val;
    }
}

// -------- Kernel 45: combine K-planes + bias + sign, then fc2 (block per n).
__global__ __launch_bounds__(256) void k45_comb_fc2(
    const double* __restrict__ Pd, const float* __restrict__ fc1b,
    const float* __restrict__ fc2w, const float* __restrict__ fc2b,
    float* __restrict__ out, int nkh)
{
    __shared__ double sj[1024];
    __shared__ double pw[4][10];
    int t = threadIdx.x, n = blockIdx.x;
    const double SCALE = 1.0 / 4294967296.0;

    #pragma unroll
    for (int rep = 0; rep < 4; rep++) {
        int j = rep * 256 + t;
        double v = 0.0;
        for (int p = 0; p < nkh; p++)
            v += Pd[(size_t)p * 1048576 + (size_t)n * 1024 + j];
        double pv = v * SCALE + (double)fc1b[j];
        sj[j] = (double)((pv > 0.0) - (pv < 0.0));
    }
    __syncthreads();

    int j0 = t * 4;
    double s0 = sj[j0], s1 = sj[j0 + 1], s2 = sj[j0 + 2], s3 = sj[j0 + 3];
    double acc[10];
    #pragma unroll
    for (int m = 0; m < 10; m++) {
        float4 w = *(const float4*)(fc2w + (size_t)m * 1024 + j0);
        acc[m] = s0 * (double)w.x + s1 * (double)w.y + s2 * (double)w.z + s3 * (double)w.w;
    }
    #pragma unroll
    for (int off = 32; off > 0; off >>= 1)
        #pragma unroll
        for (int m = 0; m < 10; m++)
            acc[m] += __shfl_down(acc[m], off);
    if ((t & 63) == 0)
        #pragma unroll
        for (int m = 0; m < 10; m++) pw[t >> 6][m] = acc[m];
    __syncthreads();
    if (t < 10)
        out[n * 10 + t] = (float)(pw[0][t] + pw[1][t] + pw[2][t] + pw[3][t] + (double)fc2b[t]);
}

// -------- Fallback (ws too small): R7-style combined k4 + old k5 via hs.
__global__ __launch_bounds__(512) void k4_fc1_mfma(
    const signed char* __restrict__ hT2, const signed char* __restrict__ BL,
    const float* __restrict__ fc1b, signed char* __restrict__ hs)
{
    __shared__ __align__(16) signed char smem[65536];
    int t = threadIdx.x, l = t & 63, wid = t >> 6;
    int nb0 = blockIdx.y * 128, jb0 = blockIdx.x * 128;
    int wn0 = (wid >> 1) * 32;
    int wj0 = (wid & 1) * 64;

    int srow = l >> 3;
    int sseg = ((l & 7) ^ srow) * 16;
    const signed char* gA = hT2 + (size_t)(nb0 + wid * 16 + srow) * 16384 + sseg;
    const signed char* gB = BL  + (size_t)(jb0 + wid * 16 + srow) * 16384 + sseg;

    v4i acc[2][4];
    #pragma unroll
    for (int i = 0; i < 2; i++)
        #pragma unroll
        for (int q = 0; q < 4; q++) acc[i][q] = (v4i){0, 0, 0, 0};

    {
        signed char* As = smem;
        signed char* Bs = smem + 16384;
        #pragma unroll
        for (int i = 0; i < 2; i++) {
            async16(gA + (size_t)i * 8 * 16384, As + (wid * 16 + i * 8) * 128);
            async16(gB + (size_t)i * 8 * 16384, Bs + (wid * 16 + i * 8) * 128);
        }
    }

    for (int it = 0; it < 128; it++) {
        __syncthreads();
        if (it + 1 < 128) {
            int kt = (it + 1) * 128;
            signed char* As = smem + ((it + 1) & 1) * 32768;
            signed char* Bs = As + 16384;
            #pragma unroll
            for (int i = 0; i < 2; i++) {
                async16(gA + (size_t)i * 8 * 16384 + kt, As + (wid * 16 + i * 8) * 128);
                async16(gB + (size_t)i * 8 * 16384 + kt, Bs + (wid * 16 + i * 8) * 128);
            }
        }
        const signed char* As = smem + (it & 1) * 32768;
        const signed char* Bs = As + 16384;
        #pragma unroll
        for (int ks = 0; ks < 2; ks++) {
            int sw = (((ks * 4) + (l >> 4)) ^ (l & 7)) * 16;
            v4i af[2], bf[4];
            #pragma unroll
            for (int i = 0; i < 2; i++)
                af[i] = *(const v4i*)&As[(wn0 + i * 16 + (l & 15)) * 128 + sw];
            #pragma unroll
            for (int q = 0; q < 4; q++)
                bf[q] = *(const v4i*)&Bs[(wj0 + q * 16 + (l & 15)) * 128 + sw];
            #pragma unroll
            for (int i = 0; i < 2; i++)
                #pragma unroll
                for (int q = 0; q < 4; q++)
                    acc[i][q] = __builtin_amdgcn_mfma_i32_16x16x64_i8(af[i], bf[q], acc[i][q], 0, 0, 0);
        }
    }

    __syncthreads();
    int* S = (int*)smem;
    #pragma unroll
    for (int i = 0; i < 2; i++)
        #pragma unroll
        for (int q = 0; q < 4; q++)
            #pragma unroll
            for (int rr = 0; rr < 4; rr++) {
                int n_l  = wn0 + i * 16 + (l >> 4) * 4 + rr;
                int jm_l = wj0 + q * 16 + (l & 15);
                S[n_l * 128 + jm_l] = acc[i][q][rr];
            }
    __syncthreads();

    const double SCALE = 1.0 / 4294967296.0;
    #pragma unroll
    for (int i = 0; i < 8; i++) {
        int idx = t * 8 + i;
        int n_l = idx >> 5, j_l = idx & 31;
        int4 s = *(const int4*)&S[n_l * 128 + j_l * 4];
        double val = (double)s.x + 128.0 * (double)s.y
                   + 16384.0 * (double)s.z + 2097152.0 * (double)s.w;
        int j = blockIdx.x * 32 + j_l;
        double p = val * SCALE + (double)fc1b[j];
        hs[(size_t)(nb0 + n_l) * 1024 + j] = (signed char)((p > 0.0) - (p < 0.0));
    }
}

__global__ void k5_fc2(const signed char* __restrict__ hs,
                       const float* __restrict__ fc2w, const float* __restrict__ fc2b,
                       float* __restrict__ out)
{
    int idx = blockIdx.x * 64 + threadIdx.x;
    if (idx >= 10240) return;
    int n = idx / 10, m = idx - n * 10;
    const signed char* hr = hs + (size_t)n * 1024;
    const float* wr = fc2w + (size_t)m * 1024;
    double acc = (double)fc2b[m];
    for (int jb = 0; jb < 1024; jb += 16) {
        int4 hv = *(const int4*)(hr + jb);
        int wd[4] = {hv.x, hv.y, hv.z, hv.w};
        #pragma unroll
        for (int u = 0; u < 4; u++)
            #pragma unroll
            for (int e = 0; e < 4; e++)
                acc += (double)(signed char)(wd[u] >> (8 * e)) * (double)wr[jb + u * 4 + e];
    }
    out[idx] = (float)acc;
}

extern "C" void kernel_launch(void* const* d_in, const int* in_sizes, int n_in,
                              void* d_out, int out_size, void* d_ws, size_t ws_size,
                              hipStream_t stream)
{
    const float* x    = (const float*)d_in[0];
    const float* w1dw = (const float*)d_in[1];
    const float* b1dw = (const float*)d_in[2];
    const float* w1pw = (const float*)d_in[3];
    const float* b1pw = (const float*)d_in[4];
    const float* w2dw = (const float*)d_in[5];
    const float* b2dw = (const float*)d_in[6];
    const float* w2pw = (const float*)d_in[7];
    const float* b2pw = (const float*)d_in[8];
    const float* fc1w = (const float*)d_in[9];
    const float* fc1b = (const float*)d_in[10];
    const float* fc2w = (const float*)d_in[11];
    const float* fc2b = (const float*)d_in[12];
    float* out = (float*)d_out;

    // workspace:
    //   pooled1T @0        33.5MB  (dead after k3_fused)
    //   BL       @0        64MiB   (written by kprep after k3_fused)
    //   hT2      @64MiB    16MiB
    //   w2s/b2adj@80MiB    33KB    (dead after k3_fused)
    //   hs       @80MiB    1MiB    (fallback path only)
    //   Pd       @84934656 16MiB (kh=2) or 32MiB (kh=4) fp64 K-split partials
    char* ws = (char*)d_ws;
    signed char* pooled1T = (signed char*)(ws);
    signed char* hT2      = (signed char*)(ws + 67108864);
    signed char* w2s      = (signed char*)(ws + 83886080);
    int*         b2adj    = (int*)(ws + 83886080 + 32768);
    signed char* BL       = (signed char*)(ws);
    signed char* hs       = (signed char*)(ws + 83886080);
    double*      Pd       = (double*)(ws + 84934656);
    bool split4 = ws_size >= (size_t)84934656 + 33554432;
    bool split2 = ws_size >= (size_t)84934656 + 16777216;

    hipLaunchKernelGGL(k1_conv1,  dim3(1024),  dim3(256), 0, stream,
                       x, w1dw, b1dw, w1pw, b1pw, w2pw, b2pw, pooled1T, w2s, b2adj);
    hipLaunchKernelGGL(k3_fused,  dim3(1024),  dim3(256), 0, stream,
                       pooled1T, w2dw, b2dw, w2s, b2adj, hT2);
    hipLaunchKernelGGL(kprep,     dim3(16384), dim3(256), 0, stream,
                       fc1w, BL);
    if (split4) {
        hipLaunchKernelGGL(k4a_fc1<4096>, dim3(32, 8, 4), dim3(512), 0, stream,
                           hT2, BL, Pd);
        hipLaunchKernelGGL(k45_comb_fc2,  dim3(1024),     dim3(256), 0, stream,
                           Pd, fc1b, fc2w, fc2b, out, 4);
    } else if (split2) {
        hipLaunchKernelGGL(k4a_fc1<8192>, dim3(32, 8, 2), dim3(512), 0, stream,
                           hT2, BL, Pd);
        hipLaunchKernelGGL(k45_comb_fc2,  dim3(1024),     dim3(256), 0, stream,
                           Pd, fc1b, fc2w, fc2b, out, 2);
    } else {
        hipLaunchKernelGGL(k4_fc1_mfma, dim3(32, 8), dim3(512), 0, stream,
                           hT2, BL, fc1b, hs);
        hipLaunchKernelGGL(k5_fc2,      dim3(160),   dim3(64),  0, stream,
                           hs, fc2w, fc2b, out);
    }
}

// Round 4
// 337.599 us; speedup vs baseline: 1.0372x; 1.0372x over previous
//
#include <hip/hip_runtime.h>

// BinaryConnectNet forward.
// R13: k3 staging REVERTED to coalesced int4 global read + XOR-swizzled
// ds_write (R10's swizzled-source global_load_lds tripled k3 HBM traffic:
// FETCH 26->89 MB, WRITE 43->152 MB — permuted 16B gather breaks line
// coalescing). Keeps R10's LDS overlay (38912 B -> 4 blk/CU) + setprio.
// k1 epilogue: pooled1T writes now staged through LDS (was 32 scattered
// dword stores/thread at stride 128) -> 8 coalesced int4 stores/thread.
// k4a back to kh=2 (kh=4 null on k4a dur, cost extra Pd/k45 traffic).
// Math exact, absmax must stay 0.0002441406.

__device__ __forceinline__ int fsign(float v)  { return (v > 0.f) - (v < 0.f); }
__device__ __forceinline__ int dsign(double v) { return (v > 0.0) - (v < 0.0); }

typedef int v4i __attribute__((ext_vector_type(4)));

__device__ __forceinline__ void async16(const signed char* g, signed char* l) {
    __builtin_amdgcn_global_load_lds(
        (const __attribute__((address_space(1))) void*)g,
        (__attribute__((address_space(3))) void*)l, 16, 0, 0);
}

// -------- Kernel 1: conv1 dw(3x3,g=3) + pw(1x1 3->128) + sign + maxpool2
// -> pooled1T [n][y16][x16][c128] int8. Block b handles image n=b (256 px).
// Epilogue staged via LDS for coalesced global writes.
// Block 0 additionally performs the conv2-pw prep (former kprep2).
__global__ void k1_conv1(const float* __restrict__ x,
                         const float* __restrict__ w1dw, const float* __restrict__ b1dw,
                         const float* __restrict__ w1pw, const float* __restrict__ b1pw,
                         const float* __restrict__ w2pw, const float* __restrict__ b2pw,
                         signed char* __restrict__ pooled1T,
                         signed char* __restrict__ w2s, int* __restrict__ b2adj)
{
    __shared__ float sdw[27], sbdw[3];
    __shared__ unsigned char spidx[128];
    __shared__ __align__(16) signed char Obuf[32768];
    int t = threadIdx.x;
    if (t < 27) sdw[t] = (float)fsign(w1dw[t]);
    if (t < 3)  sbdw[t] = (float)fsign(b1dw[t]);
    if (t < 128) {
        int b0 = w1pw[t * 3 + 0] > 0.f;
        int b1 = w1pw[t * 3 + 1] > 0.f;
        int b2 = w1pw[t * 3 + 2] > 0.f;
        int b3 = b1pw[t] > 0.f;
        spidx[t] = (unsigned char)(b0 | (b1 << 1) | (b2 << 2) | (b3 << 3));
    }
    __syncthreads();

    int g  = blockIdx.x * 256 + t;
    int px = g & 15, py = (g >> 4) & 15, n = g >> 8;

    double h[3][4];
    const float* xb = x + (size_t)n * 3 * 1024;
    #pragma unroll
    for (int c = 0; c < 3; c++) {
        const float* xc = xb + c * 1024;
        #pragma unroll
        for (int dy = 0; dy < 2; dy++)
        #pragma unroll
        for (int dx = 0; dx < 2; dx++) {
            int y = 2 * py + dy, xx = 2 * px + dx;
            double acc = (double)sbdw[c];
            #pragma unroll
            for (int ky = 0; ky < 3; ky++) {
                int yy = y + ky - 1;
                if (yy < 0 || yy > 31) continue;
                #pragma unroll
                for (int kx = 0; kx < 3; kx++) {
                    int xxx = xx + kx - 1;
                    if (xxx < 0 || xxx > 31) continue;
                    acc += (double)sdw[c * 9 + ky * 3 + kx] * (double)xc[yy * 32 + xxx];
                }
            }
            h[c][dy * 2 + dx] = acc;
        }
    }

    double tv[4][4];
    #pragma unroll
    for (int q = 0; q < 4; q++) {
        double u = h[0][q] + h[1][q];
        double v = h[0][q] - h[1][q];
        tv[0][q] = v - h[2][q];
        tv[1][q] = u - h[2][q];
        tv[2][q] = v + h[2][q];
        tv[3][q] = u + h[2][q];
    }
    int mpack = 0;
    #pragma unroll
    for (int bp = 0; bp < 4; bp++) {
        int mxP = -2, mnP = 2, mxM = -2, mnM = 2;
        #pragma unroll
        for (int q = 0; q < 4; q++) {
            int sP = dsign(tv[bp][q] + 1.0);
            int sM = dsign(tv[bp][q] - 1.0);
            mxP = max(mxP, sP); mnP = min(mnP, sP);
            mxM = max(mxM, sM); mnM = min(mnM, sM);
        }
        int pat1 = 1 | (bp << 1);
        int pat0 = (~pat1) & 7;
        mpack |= (mxP + 1)   << (2 * (pat1 | 8));
        mpack |= (mxM + 1)   << (2 * pat1);
        mpack |= ((-mnM) + 1) << (2 * (pat0 | 8));
        mpack |= ((-mnP) + 1) << (2 * pat0);
    }

    // Stage this pixel's 128 channel bytes into LDS row t, 16B-XOR swizzled
    // (caps ds_write conflicts at ~8-way vs 32-way unswizzled).
    signed char* orow = Obuf + t * 128;
    const int* pint = (const int*)spidx;
    for (int ob = 0; ob < 32; ob++) {
        int pw = pint[ob];
        int cur = 0;
        #pragma unroll
        for (int e = 0; e < 4; e++) {
            int pi = (pw >> (8 * e)) & 15;
            int mv = ((mpack >> (pi * 2)) & 3) - 1;
            cur |= (mv & 0xff) << (8 * e);
        }
        int ad = (((ob >> 2) ^ (t & 7)) << 4) + (ob & 3) * 4;
        *(int*)(orow + ad) = cur;
    }
    __syncthreads();

    // Coalesced copy: pixel index == LDS row == global (py*16+px).
    signed char* outb = pooled1T + (size_t)blockIdx.x * 32768;
    #pragma unroll
    for (int r = 0; r < 8; r++) {
        int o = r * 4096 + t * 16;
        int pix = o >> 7, gg = (o >> 4) & 7;
        *(int4*)(outb + o) = *(const int4*)&Obuf[pix * 128 + ((gg ^ (pix & 7)) << 4)];
    }

    // Fused former kprep2 (block 0 only): w2s sign matrix + b2adj.
    if (blockIdx.x == 0) {
        int o = t;   // 256 threads -> 256 outputs
        int rs = 0;
        for (int cq = 0; cq < 32; cq++) {
            float4 w = *(const float4*)(w2pw + (size_t)o * 128 + cq * 4);
            int s0 = fsign(w.x), s1 = fsign(w.y), s2 = fsign(w.z), s3 = fsign(w.w);
            rs += s0 + s1 + s2 + s3;
            int pk = (s0 & 0xff) | ((s1 & 0xff) << 8) | ((s2 & 0xff) << 16) | ((s3 & 0xff) << 24);
            *(int*)(w2s + (size_t)o * 128 + cq * 4) = pk;
        }
        b2adj[o] = fsign(b2pw[o]) - 32 * rs;
    }
}

// -------- Kernel 3 (fused): depthwise conv2 + pointwise MFMA GEMM + sign + maxpool
// LDS 38912 B -> 4 blocks/CU co-resident. Staging: coalesced global int4
// read + swizzled ds_write (R0-verified traffic: FETCH ~26 MB, WRITE ~43 MB).
__global__ __launch_bounds__(256, 4) void k3_fused(
    const signed char* __restrict__ pooled1T,
    const float* __restrict__ w2dw, const float* __restrict__ b2dw,
    const signed char* __restrict__ w2s, const int* __restrict__ b2adj,
    signed char* __restrict__ hT2)
{
    __shared__ __align__(16) signed char Ps[32768];
    // Phase A (staging + dw conv): sw4[1152] + sdb2[128].
    // Phase B (oc loop, after the first post-MFMA barrier): Os[64*80].
    __shared__ __align__(16) signed char Uni[5120];
    __shared__ int sb2adj[256];

    signed char* sw4  = Uni;
    signed char* sdb2 = Uni + 1152;
    signed char* Os   = Uni;

    int t = threadIdx.x, l = t & 63, wid = t >> 6;
    int n = blockIdx.x;
    const signed char* pb = pooled1T + (size_t)n * 32768;

    #pragma unroll
    for (int it = 0; it < 8; it++) {
        int off = it * 4096 + t * 16;
        int p = off >> 7, seg = (off >> 4) & 7;
        *(int4*)&Ps[p * 128 + ((seg ^ (p & 7)) * 16)] = *(const int4*)(pb + off);
    }
    for (int i = t; i < 1152; i += 256) {
        int c = i & 127, tap = i >> 7;
        sw4[tap * 128 + c] = (signed char)fsign(w2dw[c * 9 + tap]);
    }
    if (t < 128) sdb2[t] = (signed char)(fsign(b2dw[t]) + 1);
    if (t < 256) sb2adj[t] = b2adj[t];
    __syncthreads();

    int frow = l & 15;

    v4i af[4][2];
    #pragma unroll
    for (int ks = 0; ks < 2; ks++) {
        int c0 = ks * 64 + (l >> 4) * 16;
        int cc = c0 >> 4;
        int4 w4[9];
        #pragma unroll
        for (int tap = 0; tap < 9; tap++)
            w4[tap] = *(const int4*)&sw4[tap * 128 + c0];
        int4 sdbv = *(const int4*)&sdb2[c0];

        #pragma unroll
        for (int i = 0; i < 4; i++) {
            int r = (wid * 4 + i) * 16 + frow;
            int py = r >> 5, px2 = (r >> 2) & 7, dy = (r >> 1) & 1, dx = r & 1;
            int y = 2 * py + dy, x = 2 * px2 + dx;
            int4 cnt = (int4){0, 0, 0, 0};
            #pragma unroll
            for (int ky = 0; ky < 3; ky++) {
                int yy = y + ky - 1;
                int yc = min(max(yy, 0), 15);
                #pragma unroll
                for (int kx = 0; kx < 3; kx++) {
                    int xx2 = x + kx - 1;
                    int xc = min(max(xx2, 0), 15);
                    int inb = ((yy == yc) && (xx2 == xc)) ? 0x01010101 : 0;
                    int p = yc * 16 + xc;
                    int4 v = *(const int4*)&Ps[p * 128 + ((cc ^ (p & 7)) * 16)];
                    int4 w = w4[ky * 3 + kx];
                    cnt.x += ((v.x ^ w.x) >> 1) & inb;
                    cnt.y += ((v.y ^ w.y) >> 1) & inb;
                    cnt.z += ((v.z ^ w.z) >> 1) & inb;
                    cnt.w += ((v.w ^ w.w) >> 1) & inb;
                }
            }
            int valid = (1 + (y > 0) + (y < 15)) * (1 + (x > 0) + (x < 15));
            int mb = (valid + 31) * 0x01010101;
            int4 u;
            u.x = sdbv.x + mb - (cnt.x + cnt.x);
            u.y = sdbv.y + mb - (cnt.y + cnt.y);
            u.z = sdbv.z + mb - (cnt.z + cnt.z);
            u.w = sdbv.w + mb - (cnt.w + cnt.w);
            af[i][ks] = (v4i){u.x, u.y, u.z, u.w};
        }
    }

    for (int oc = 0; oc < 4; oc++) {
        v4i acc[4][4];
        #pragma unroll
        for (int i = 0; i < 4; i++)
            #pragma unroll
            for (int jt = 0; jt < 4; jt++) acc[i][jt] = (v4i){0, 0, 0, 0};

        #pragma unroll
        for (int ks = 0; ks < 2; ks++) {
            v4i bf[4];
            #pragma unroll
            for (int jt = 0; jt < 4; jt++)
                bf[jt] = *(const v4i*)(w2s + (size_t)(oc * 64 + jt * 16 + frow) * 128
                                       + ks * 64 + (l >> 4) * 16);
            __builtin_amdgcn_s_setprio(1);
            #pragma unroll
            for (int i = 0; i < 4; i++)
                #pragma unroll
                for (int jt = 0; jt < 4; jt++)
                    acc[i][jt] = __builtin_amdgcn_mfma_i32_16x16x64_i8(af[i][ks], bf[jt], acc[i][jt], 0, 0, 0);
            __builtin_amdgcn_s_setprio(0);
        }

        __syncthreads();
        // From here Uni is the Os staging buffer (sw4/sdb2 dead).
        #pragma unroll
        for (int jt = 0; jt < 4; jt++) {
            int o_l = jt * 16 + frow;
            int bia = sb2adj[oc * 64 + o_l];
            #pragma unroll
            for (int i = 0; i < 4; i++) {
                int mx = -2;
                #pragma unroll
                for (int rr = 0; rr < 4; rr++) {
                    int p = acc[i][jt][rr] + bia;
                    int s = (p > 0) - (p < 0);
                    mx = s > mx ? s : mx;
                }
                int pp = (wid * 4 + i) * 4 + (l >> 4);
                Os[o_l * 80 + pp] = (signed char)mx;
            }
        }
        __syncthreads();
        *(int4*)&hT2[(size_t)n * 16384 + oc * 4096 + t * 16]
            = *(const int4*)&Os[(t >> 2) * 80 + (t & 3) * 16];
    }
}

// -------- Prep: fc1_w -> 4 signed radix-128 int8 limbs on 2^-32 grid (exact).
__global__ void kprep(const float* __restrict__ fc1w, signed char* __restrict__ BL)
{
    int t = threadIdx.x;
    int b = blockIdx.x;
    int j = b >> 4, kb = b & 15;
    int k0 = kb * 1024 + t * 4;
    float4 w = *(const float4*)(fc1w + (size_t)j * 16384 + k0);
    float we[4] = {w.x, w.y, w.z, w.w};
    int out[4] = {0, 0, 0, 0};
    #pragma unroll
    for (int e = 0; e < 4; e++) {
        int q = (int)rint((double)we[e] * 4294967296.0);
        q = min(max(q, -266338304), 266338304);
        int d0 = ((q + 64) & 127) - 64; q = (q - d0) >> 7;
        int d1 = ((q + 64) & 127) - 64; q = (q - d1) >> 7;
        int d2 = ((q + 64) & 127) - 64; q = (q - d2) >> 7;
        int d3 = q;
        out[0] |= (d0 & 0xff) << (8 * e);
        out[1] |= (d1 & 0xff) << (8 * e);
        out[2] |= (d2 & 0xff) << (8 * e);
        out[3] |= (d3 & 0xff) << (8 * e);
    }
    #pragma unroll
    for (int m = 0; m < 4; m++)
        *(int*)(BL + (size_t)(j * 4 + m) * 16384 + k0) = out[m];
}

// -------- Kernel 4a: fc1 GEMM, K-split x2 grid + K-phase-split waves.
// Proven R9 2-buffer structure (2 blocks/CU; single-tile lookahead already
// hides staging latency — deeper pipelines at 1 blk/CU measured worse).
__global__ __launch_bounds__(512, 4) void k4a_fc1(
    const signed char* __restrict__ hT2, const signed char* __restrict__ BL,
    double* __restrict__ Pd)
{
    __shared__ __align__(16) signed char smem[65536];
    int t = threadIdx.x, l = t & 63, wid = t >> 6;
    int nb0 = blockIdx.y * 128, jb0 = blockIdx.x * 128;
    int kh = blockIdx.z, k0 = kh * 8192;
    int ksw = wid >> 2;                       // K-phase of this wave
    int wn0 = ((wid >> 1) & 1) * 64, wj0 = (wid & 1) * 64;

    int srow = l >> 3;
    int sseg = ((l & 7) ^ srow) * 16;
    const signed char* gA = hT2 + (size_t)(nb0 + wid * 16 + srow) * 16384 + k0 + sseg;
    const signed char* gB = BL  + (size_t)(jb0 + wid * 16 + srow) * 16384 + k0 + sseg;

    v4i acc[4][4];
    #pragma unroll
    for (int i = 0; i < 4; i++)
        #pragma unroll
        for (int q = 0; q < 4; q++) acc[i][q] = (v4i){0, 0, 0, 0};

    {
        signed char* As = smem;
        signed char* Bs = smem + 16384;
        #pragma unroll
        for (int c = 0; c < 2; c++) {
            async16(gA + (size_t)c * 8 * 16384, As + (wid * 16 + c * 8) * 128);
            async16(gB + (size_t)c * 8 * 16384, Bs + (wid * 16 + c * 8) * 128);
        }
    }

    int sw = (((ksw * 4) + (l >> 4)) ^ (l & 7)) * 16;

    for (int it = 0; it < 64; it++) {
        __syncthreads();
        if (it + 1 < 64) {
            int kt = (it + 1) * 128;
            signed char* As = smem + ((it + 1) & 1) * 32768;
            signed char* Bs = As + 16384;
            #pragma unroll
            for (int c = 0; c < 2; c++) {
                async16(gA + (size_t)c * 8 * 16384 + kt, As + (wid * 16 + c * 8) * 128);
                async16(gB + (size_t)c * 8 * 16384 + kt, Bs + (wid * 16 + c * 8) * 128);
            }
        }
        const signed char* As = smem + (it & 1) * 32768;
        const signed char* Bs = As + 16384;
        v4i af[4], bf[4];
        #pragma unroll
        for (int i = 0; i < 4; i++)
            af[i] = *(const v4i*)&As[(wn0 + i * 16 + (l & 15)) * 128 + sw];
        #pragma unroll
        for (int q = 0; q < 4; q++)
            bf[q] = *(const v4i*)&Bs[(wj0 + q * 16 + (l & 15)) * 128 + sw];
        #pragma unroll
        for (int i = 0; i < 4; i++)
            #pragma unroll
            for (int q = 0; q < 4; q++)
                acc[i][q] = __builtin_amdgcn_mfma_i32_16x16x64_i8(af[i], bf[q], acc[i][q], 0, 0, 0);
    }

    __syncthreads();
    int* S = (int*)smem;    // [128 n][128 jm]
    if (ksw == 0) {
        #pragma unroll
        for (int i = 0; i < 4; i++)
            #pragma unroll
            for (int q = 0; q < 4; q++)
                #pragma unroll
                for (int rr = 0; rr < 4; rr++) {
                    int n_l  = wn0 + i * 16 + (l >> 4) * 4 + rr;
                    int jm_l = wj0 + q * 16 + (l & 15);
                    S[n_l * 128 + jm_l] = acc[i][q][rr];
                }
    }
    __syncthreads();
    if (ksw == 1) {
        #pragma unroll
        for (int i = 0; i < 4; i++)
            #pragma unroll
            for (int q = 0; q < 4; q++)
                #pragma unroll
                for (int rr = 0; rr < 4; rr++) {
                    int n_l  = wn0 + i * 16 + (l >> 4) * 4 + rr;
                    int jm_l = wj0 + q * 16 + (l & 15);
                    S[n_l * 128 + jm_l] += acc[i][q][rr];
                }
    }
    __syncthreads();

    #pragma unroll
    for (int e = 0; e < 8; e++) {
        int idx = t * 8 + e;                 // 4096 = 128 n x 32 j
        int n_l = idx >> 5, j_l = idx & 31;
        int4 s = *(const int4*)&S[n_l * 128 + j_l * 4];
        double val = (double)s.x + 128.0 * (double)s.y
                   + 16384.0 * (double)s.z + 2097152.0 * (double)s.w;
        Pd[(size_t)kh * 1048576 + (size_t)(nb0 + n_l) * 1024 + blockIdx.x * 32 + j_l] = val;
    }
}

// -------- Kernel 45: combine K-halves + bias + sign, then fc2 (block per n).
__global__ __launch_bounds__(256) void k45_comb_fc2(
    const double* __restrict__ Pd, const float* __restrict__ fc1b,
    const float* __restrict__ fc2w, const float* __restrict__ fc2b,
    float* __restrict__ out)
{
    __shared__ double sj[1024];
    __shared__ double pw[4][10];
    int t = threadIdx.x, n = blockIdx.x;
    const double SCALE = 1.0 / 4294967296.0;

    #pragma unroll
    for (int rep = 0; rep < 4; rep++) {
        int j = rep * 256 + t;
        double v = Pd[(size_t)n * 1024 + j] + Pd[1048576 + (size_t)n * 1024 + j];
        double p = v * SCALE + (double)fc1b[j];
        sj[j] = (double)((p > 0.0) - (p < 0.0));
    }
    __syncthreads();

    int j0 = t * 4;
    double s0 = sj[j0], s1 = sj[j0 + 1], s2 = sj[j0 + 2], s3 = sj[j0 + 3];
    double acc[10];
    #pragma unroll
    for (int m = 0; m < 10; m++) {
        float4 w = *(const float4*)(fc2w + (size_t)m * 1024 + j0);
        acc[m] = s0 * (double)w.x + s1 * (double)w.y + s2 * (double)w.z + s3 * (double)w.w;
    }
    #pragma unroll
    for (int off = 32; off > 0; off >>= 1)
        #pragma unroll
        for (int m = 0; m < 10; m++)
            acc[m] += __shfl_down(acc[m], off);
    if ((t & 63) == 0)
        #pragma unroll
        for (int m = 0; m < 10; m++) pw[t >> 6][m] = acc[m];
    __syncthreads();
    if (t < 10)
        out[n * 10 + t] = (float)(pw[0][t] + pw[1][t] + pw[2][t] + pw[3][t] + (double)fc2b[t]);
}

// -------- Fallback (ws too small): R7-style combined k4 + old k5 via hs.
__global__ __launch_bounds__(512) void k4_fc1_mfma(
    const signed char* __restrict__ hT2, const signed char* __restrict__ BL,
    const float* __restrict__ fc1b, signed char* __restrict__ hs)
{
    __shared__ __align__(16) signed char smem[65536];
    int t = threadIdx.x, l = t & 63, wid = t >> 6;
    int nb0 = blockIdx.y * 128, jb0 = blockIdx.x * 128;
    int wn0 = (wid >> 1) * 32;
    int wj0 = (wid & 1) * 64;

    int srow = l >> 3;
    int sseg = ((l & 7) ^ srow) * 16;
    const signed char* gA = hT2 + (size_t)(nb0 + wid * 16 + srow) * 16384 + sseg;
    const signed char* gB = BL  + (size_t)(jb0 + wid * 16 + srow) * 16384 + sseg;

    v4i acc[2][4];
    #pragma unroll
    for (int i = 0; i < 2; i++)
        #pragma unroll
        for (int q = 0; q < 4; q++) acc[i][q] = (v4i){0, 0, 0, 0};

    {
        signed char* As = smem;
        signed char* Bs = smem + 16384;
        #pragma unroll
        for (int i = 0; i < 2; i++) {
            async16(gA + (size_t)i * 8 * 16384, As + (wid * 16 + i * 8) * 128);
            async16(gB + (size_t)i * 8 * 16384, Bs + (wid * 16 + i * 8) * 128);
        }
    }

    for (int it = 0; it < 128; it++) {
        __syncthreads();
        if (it + 1 < 128) {
            int kt = (it + 1) * 128;
            signed char* As = smem + ((it + 1) & 1) * 32768;
            signed char* Bs = As + 16384;
            #pragma unroll
            for (int i = 0; i < 2; i++) {
                async16(gA + (size_t)i * 8 * 16384 + kt, As + (wid * 16 + i * 8) * 128);
                async16(gB + (size_t)i * 8 * 16384 + kt, Bs + (wid * 16 + i * 8) * 128);
            }
        }
        const signed char* As = smem + (it & 1) * 32768;
        const signed char* Bs = As + 16384;
        #pragma unroll
        for (int ks = 0; ks < 2; ks++) {
            int sw = (((ks * 4) + (l >> 4)) ^ (l & 7)) * 16;
            v4i af[2], bf[4];
            #pragma unroll
            for (int i = 0; i < 2; i++)
                af[i] = *(const v4i*)&As[(wn0 + i * 16 + (l & 15)) * 128 + sw];
            #pragma unroll
            for (int q = 0; q < 4; q++)
                bf[q] = *(const v4i*)&Bs[(wj0 + q * 16 + (l & 15)) * 128 + sw];
            #pragma unroll
            for (int i = 0; i < 2; i++)
                #pragma unroll
                for (int q = 0; q < 4; q++)
                    acc[i][q] = __builtin_amdgcn_mfma_i32_16x16x64_i8(af[i], bf[q], acc[i][q], 0, 0, 0);
        }
    }

    __syncthreads();
    int* S = (int*)smem;
    #pragma unroll
    for (int i = 0; i < 2; i++)
        #pragma unroll
        for (int q = 0; q < 4; q++)
            #pragma unroll
            for (int rr = 0; rr < 4; rr++) {
                int n_l  = wn0 + i * 16 + (l >> 4) * 4 + rr;
                int jm_l = wj0 + q * 16 + (l & 15);
                S[n_l * 128 + jm_l] = acc[i][q][rr];
            }
    __syncthreads();

    const double SCALE = 1.0 / 4294967296.0;
    #pragma unroll
    for (int i = 0; i < 8; i++) {
        int idx = t * 8 + i;
        int n_l = idx >> 5, j_l = idx & 31;
        int4 s = *(const int4*)&S[n_l * 128 + j_l * 4];
        double val = (double)s.x + 128.0 * (double)s.y
                   + 16384.0 * (double)s.z + 2097152.0 * (double)s.w;
        int j = blockIdx.x * 32 + j_l;
        double p = val * SCALE + (double)fc1b[j];
        hs[(size_t)(nb0 + n_l) * 1024 + j] = (signed char)((p > 0.0) - (p < 0.0));
    }
}

__global__ void k5_fc2(const signed char* __restrict__ hs,
                       const float* __restrict__ fc2w, const float* __restrict__ fc2b,
                       float* __restrict__ out)
{
    int idx = blockIdx.x * 64 + threadIdx.x;
    if (idx >= 10240) return;
    int n = idx / 10, m = idx - n * 10;
    const signed char* hr = hs + (size_t)n * 1024;
    const float* wr = fc2w + (size_t)m * 1024;
    double acc = (double)fc2b[m];
    for (int jb = 0; jb < 1024; jb += 16) {
        int4 hv = *(const int4*)(hr + jb);
        int wd[4] = {hv.x, hv.y, hv.z, hv.w};
        #pragma unroll
        for (int u = 0; u < 4; u++)
            #pragma unroll
            for (int e = 0; e < 4; e++)
                acc += (double)(signed char)(wd[u] >> (8 * e)) * (double)wr[jb + u * 4 + e];
    }
    out[idx] = (float)acc;
}

extern "C" void kernel_launch(void* const* d_in, const int* in_sizes, int n_in,
                              void* d_out, int out_size, void* d_ws, size_t ws_size,
                              hipStream_t stream)
{
    const float* x    = (const float*)d_in[0];
    const float* w1dw = (const float*)d_in[1];
    const float* b1dw = (const float*)d_in[2];
    const float* w1pw = (const float*)d_in[3];
    const float* b1pw = (const float*)d_in[4];
    const float* w2dw = (const float*)d_in[5];
    const float* b2dw = (const float*)d_in[6];
    const float* w2pw = (const float*)d_in[7];
    const float* b2pw = (const float*)d_in[8];
    const float* fc1w = (const float*)d_in[9];
    const float* fc1b = (const float*)d_in[10];
    const float* fc2w = (const float*)d_in[11];
    const float* fc2b = (const float*)d_in[12];
    float* out = (float*)d_out;

    // workspace:
    //   pooled1T @0        33.5MB  (dead after k3_fused)
    //   BL       @0        64MiB   (written by kprep after k3_fused)
    //   hT2      @64MiB    16MiB
    //   w2s/b2adj@80MiB    33KB    (dead after k3_fused)
    //   hs       @80MiB    1MiB    (fallback path only)
    //   Pd       @84934656 16MiB   fp64 K-split partials
    char* ws = (char*)d_ws;
    signed char* pooled1T = (signed char*)(ws);
    signed char* hT2      = (signed char*)(ws + 67108864);
    signed char* w2s      = (signed char*)(ws + 83886080);
    int*         b2adj    = (int*)(ws + 83886080 + 32768);
    signed char* BL       = (signed char*)(ws);
    signed char* hs       = (signed char*)(ws + 83886080);
    double*      Pd       = (double*)(ws + 84934656);
    bool split = ws_size >= (size_t)84934656 + 16777216;

    hipLaunchKernelGGL(k1_conv1,  dim3(1024),  dim3(256), 0, stream,
                       x, w1dw, b1dw, w1pw, b1pw, w2pw, b2pw, pooled1T, w2s, b2adj);
    hipLaunchKernelGGL(k3_fused,  dim3(1024),  dim3(256), 0, stream,
                       pooled1T, w2dw, b2dw, w2s, b2adj, hT2);
    hipLaunchKernelGGL(kprep,     dim3(16384), dim3(256), 0, stream,
                       fc1w, BL);
    if (split) {
        hipLaunchKernelGGL(k4a_fc1,      dim3(32, 8, 2), dim3(512), 0, stream,
                           hT2, BL, Pd);
        hipLaunchKernelGGL(k45_comb_fc2, dim3(1024),     dim3(256), 0, stream,
                           Pd, fc1b, fc2w, fc2b, out);
    } else {
        hipLaunchKernelGGL(k4_fc1_mfma, dim3(32, 8), dim3(512), 0, stream,
                           hT2, BL, fc1b, hs);
        hipLaunchKernelGGL(k5_fc2,      dim3(160),   dim3(64),  0, stream,
                           hs, fc2w, fc2b, out);
    }
}

// Round 5
// 326.736 us; speedup vs baseline: 1.0717x; 1.0332x over previous
//
#include <hip/hip_runtime.h>

// BinaryConnectNet forward.
// R14: k4a intensity rewrite. The fc1 GEMM is 1024x4096x16384 i8 (4 limbs)
// = 137 GOP -> 35 us MFMA floor; old 64x64 wave tile made it LDS-pipe-bound
// (0.5 KB LDS read per MFMA, 1536 cyc LDS vs 1300 cyc MFMA per CU-iter).
// New: wave tile 64n x 128j (acc 128 VGPR), block 128n x 256jm, K-step 128,
// dbuf smem 96 KiB, 1 blk/CU, grid 16x8x2=256 (exact, no tail). LDS/iter
// 1125 cyc < MFMA 1306 cyc -> MFMA-bound by design. Epilogue K-phase combine
// via two 64n-half passes through a 64 KB S overlay. Swizzle formulas
// unchanged (XOR key row&7 == l&7 on both staging and read paths).
// k1/k3/kprep/k45 unchanged from R13 (k3 traffic revert verified: out of
// top-5). Math exact; absmax must stay 0.0002441406.

__device__ __forceinline__ int fsign(float v)  { return (v > 0.f) - (v < 0.f); }
__device__ __forceinline__ int dsign(double v) { return (v > 0.0) - (v < 0.0); }

typedef int v4i __attribute__((ext_vector_type(4)));

__device__ __forceinline__ void async16(const signed char* g, signed char* l) {
    __builtin_amdgcn_global_load_lds(
        (const __attribute__((address_space(1))) void*)g,
        (__attribute__((address_space(3))) void*)l, 16, 0, 0);
}

// -------- Kernel 1: conv1 dw(3x3,g=3) + pw(1x1 3->128) + sign + maxpool2
// -> pooled1T [n][y16][x16][c128] int8. Epilogue staged via LDS for
// coalesced global writes. Block 0 also does the conv2-pw prep.
__global__ void k1_conv1(const float* __restrict__ x,
                         const float* __restrict__ w1dw, const float* __restrict__ b1dw,
                         const float* __restrict__ w1pw, const float* __restrict__ b1pw,
                         const float* __restrict__ w2pw, const float* __restrict__ b2pw,
                         signed char* __restrict__ pooled1T,
                         signed char* __restrict__ w2s, int* __restrict__ b2adj)
{
    __shared__ float sdw[27], sbdw[3];
    __shared__ unsigned char spidx[128];
    __shared__ __align__(16) signed char Obuf[32768];
    int t = threadIdx.x;
    if (t < 27) sdw[t] = (float)fsign(w1dw[t]);
    if (t < 3)  sbdw[t] = (float)fsign(b1dw[t]);
    if (t < 128) {
        int b0 = w1pw[t * 3 + 0] > 0.f;
        int b1 = w1pw[t * 3 + 1] > 0.f;
        int b2 = w1pw[t * 3 + 2] > 0.f;
        int b3 = b1pw[t] > 0.f;
        spidx[t] = (unsigned char)(b0 | (b1 << 1) | (b2 << 2) | (b3 << 3));
    }
    __syncthreads();

    int g  = blockIdx.x * 256 + t;
    int px = g & 15, py = (g >> 4) & 15, n = g >> 8;

    double h[3][4];
    const float* xb = x + (size_t)n * 3 * 1024;
    #pragma unroll
    for (int c = 0; c < 3; c++) {
        const float* xc = xb + c * 1024;
        #pragma unroll
        for (int dy = 0; dy < 2; dy++)
        #pragma unroll
        for (int dx = 0; dx < 2; dx++) {
            int y = 2 * py + dy, xx = 2 * px + dx;
            double acc = (double)sbdw[c];
            #pragma unroll
            for (int ky = 0; ky < 3; ky++) {
                int yy = y + ky - 1;
                if (yy < 0 || yy > 31) continue;
                #pragma unroll
                for (int kx = 0; kx < 3; kx++) {
                    int xxx = xx + kx - 1;
                    if (xxx < 0 || xxx > 31) continue;
                    acc += (double)sdw[c * 9 + ky * 3 + kx] * (double)xc[yy * 32 + xxx];
                }
            }
            h[c][dy * 2 + dx] = acc;
        }
    }

    double tv[4][4];
    #pragma unroll
    for (int q = 0; q < 4; q++) {
        double u = h[0][q] + h[1][q];
        double v = h[0][q] - h[1][q];
        tv[0][q] = v - h[2][q];
        tv[1][q] = u - h[2][q];
        tv[2][q] = v + h[2][q];
        tv[3][q] = u + h[2][q];
    }
    int mpack = 0;
    #pragma unroll
    for (int bp = 0; bp < 4; bp++) {
        int mxP = -2, mnP = 2, mxM = -2, mnM = 2;
        #pragma unroll
        for (int q = 0; q < 4; q++) {
            int sP = dsign(tv[bp][q] + 1.0);
            int sM = dsign(tv[bp][q] - 1.0);
            mxP = max(mxP, sP); mnP = min(mnP, sP);
            mxM = max(mxM, sM); mnM = min(mnM, sM);
        }
        int pat1 = 1 | (bp << 1);
        int pat0 = (~pat1) & 7;
        mpack |= (mxP + 1)   << (2 * (pat1 | 8));
        mpack |= (mxM + 1)   << (2 * pat1);
        mpack |= ((-mnM) + 1) << (2 * (pat0 | 8));
        mpack |= ((-mnP) + 1) << (2 * pat0);
    }

    signed char* orow = Obuf + t * 128;
    const int* pint = (const int*)spidx;
    for (int ob = 0; ob < 32; ob++) {
        int pw = pint[ob];
        int cur = 0;
        #pragma unroll
        for (int e = 0; e < 4; e++) {
            int pi = (pw >> (8 * e)) & 15;
            int mv = ((mpack >> (pi * 2)) & 3) - 1;
            cur |= (mv & 0xff) << (8 * e);
        }
        int ad = (((ob >> 2) ^ (t & 7)) << 4) + (ob & 3) * 4;
        *(int*)(orow + ad) = cur;
    }
    __syncthreads();

    signed char* outb = pooled1T + (size_t)blockIdx.x * 32768;
    #pragma unroll
    for (int r = 0; r < 8; r++) {
        int o = r * 4096 + t * 16;
        int pix = o >> 7, gg = (o >> 4) & 7;
        *(int4*)(outb + o) = *(const int4*)&Obuf[pix * 128 + ((gg ^ (pix & 7)) << 4)];
    }

    if (blockIdx.x == 0) {
        int o = t;
        int rs = 0;
        for (int cq = 0; cq < 32; cq++) {
            float4 w = *(const float4*)(w2pw + (size_t)o * 128 + cq * 4);
            int s0 = fsign(w.x), s1 = fsign(w.y), s2 = fsign(w.z), s3 = fsign(w.w);
            rs += s0 + s1 + s2 + s3;
            int pk = (s0 & 0xff) | ((s1 & 0xff) << 8) | ((s2 & 0xff) << 16) | ((s3 & 0xff) << 24);
            *(int*)(w2s + (size_t)o * 128 + cq * 4) = pk;
        }
        b2adj[o] = fsign(b2pw[o]) - 32 * rs;
    }
}

// -------- Kernel 3 (fused): depthwise conv2 + pointwise MFMA GEMM + sign + maxpool
__global__ __launch_bounds__(256, 4) void k3_fused(
    const signed char* __restrict__ pooled1T,
    const float* __restrict__ w2dw, const float* __restrict__ b2dw,
    const signed char* __restrict__ w2s, const int* __restrict__ b2adj,
    signed char* __restrict__ hT2)
{
    __shared__ __align__(16) signed char Ps[32768];
    __shared__ __align__(16) signed char Uni[5120];
    __shared__ int sb2adj[256];

    signed char* sw4  = Uni;
    signed char* sdb2 = Uni + 1152;
    signed char* Os   = Uni;

    int t = threadIdx.x, l = t & 63, wid = t >> 6;
    int n = blockIdx.x;
    const signed char* pb = pooled1T + (size_t)n * 32768;

    #pragma unroll
    for (int it = 0; it < 8; it++) {
        int off = it * 4096 + t * 16;
        int p = off >> 7, seg = (off >> 4) & 7;
        *(int4*)&Ps[p * 128 + ((seg ^ (p & 7)) * 16)] = *(const int4*)(pb + off);
    }
    for (int i = t; i < 1152; i += 256) {
        int c = i & 127, tap = i >> 7;
        sw4[tap * 128 + c] = (signed char)fsign(w2dw[c * 9 + tap]);
    }
    if (t < 128) sdb2[t] = (signed char)(fsign(b2dw[t]) + 1);
    if (t < 256) sb2adj[t] = b2adj[t];
    __syncthreads();

    int frow = l & 15;

    v4i af[4][2];
    #pragma unroll
    for (int ks = 0; ks < 2; ks++) {
        int c0 = ks * 64 + (l >> 4) * 16;
        int cc = c0 >> 4;
        int4 w4[9];
        #pragma unroll
        for (int tap = 0; tap < 9; tap++)
            w4[tap] = *(const int4*)&sw4[tap * 128 + c0];
        int4 sdbv = *(const int4*)&sdb2[c0];

        #pragma unroll
        for (int i = 0; i < 4; i++) {
            int r = (wid * 4 + i) * 16 + frow;
            int py = r >> 5, px2 = (r >> 2) & 7, dy = (r >> 1) & 1, dx = r & 1;
            int y = 2 * py + dy, x = 2 * px2 + dx;
            int4 cnt = (int4){0, 0, 0, 0};
            #pragma unroll
            for (int ky = 0; ky < 3; ky++) {
                int yy = y + ky - 1;
                int yc = min(max(yy, 0), 15);
                #pragma unroll
                for (int kx = 0; kx < 3; kx++) {
                    int xx2 = x + kx - 1;
                    int xc = min(max(xx2, 0), 15);
                    int inb = ((yy == yc) && (xx2 == xc)) ? 0x01010101 : 0;
                    int p = yc * 16 + xc;
                    int4 v = *(const int4*)&Ps[p * 128 + ((cc ^ (p & 7)) * 16)];
                    int4 w = w4[ky * 3 + kx];
                    cnt.x += ((v.x ^ w.x) >> 1) & inb;
                    cnt.y += ((v.y ^ w.y) >> 1) & inb;
                    cnt.z += ((v.z ^ w.z) >> 1) & inb;
                    cnt.w += ((v.w ^ w.w) >> 1) & inb;
                }
            }
            int valid = (1 + (y > 0) + (y < 15)) * (1 + (x > 0) + (x < 15));
            int mb = (valid + 31) * 0x01010101;
            int4 u;
            u.x = sdbv.x + mb - (cnt.x + cnt.x);
            u.y = sdbv.y + mb - (cnt.y + cnt.y);
            u.z = sdbv.z + mb - (cnt.z + cnt.z);
            u.w = sdbv.w + mb - (cnt.w + cnt.w);
            af[i][ks] = (v4i){u.x, u.y, u.z, u.w};
        }
    }

    for (int oc = 0; oc < 4; oc++) {
        v4i acc[4][4];
        #pragma unroll
        for (int i = 0; i < 4; i++)
            #pragma unroll
            for (int jt = 0; jt < 4; jt++) acc[i][jt] = (v4i){0, 0, 0, 0};

        #pragma unroll
        for (int ks = 0; ks < 2; ks++) {
            v4i bf[4];
            #pragma unroll
            for (int jt = 0; jt < 4; jt++)
                bf[jt] = *(const v4i*)(w2s + (size_t)(oc * 64 + jt * 16 + frow) * 128
                                       + ks * 64 + (l >> 4) * 16);
            __builtin_amdgcn_s_setprio(1);
            #pragma unroll
            for (int i = 0; i < 4; i++)
                #pragma unroll
                for (int jt = 0; jt < 4; jt++)
                    acc[i][jt] = __builtin_amdgcn_mfma_i32_16x16x64_i8(af[i][ks], bf[jt], acc[i][jt], 0, 0, 0);
            __builtin_amdgcn_s_setprio(0);
        }

        __syncthreads();
        #pragma unroll
        for (int jt = 0; jt < 4; jt++) {
            int o_l = jt * 16 + frow;
            int bia = sb2adj[oc * 64 + o_l];
            #pragma unroll
            for (int i = 0; i < 4; i++) {
                int mx = -2;
                #pragma unroll
                for (int rr = 0; rr < 4; rr++) {
                    int p = acc[i][jt][rr] + bia;
                    int s = (p > 0) - (p < 0);
                    mx = s > mx ? s : mx;
                }
                int pp = (wid * 4 + i) * 4 + (l >> 4);
                Os[o_l * 80 + pp] = (signed char)mx;
            }
        }
        __syncthreads();
        *(int4*)&hT2[(size_t)n * 16384 + oc * 4096 + t * 16]
            = *(const int4*)&Os[(t >> 2) * 80 + (t & 3) * 16];
    }
}

// -------- Prep: fc1_w -> 4 signed radix-128 int8 limbs on 2^-32 grid (exact).
__global__ void kprep(const float* __restrict__ fc1w, signed char* __restrict__ BL)
{
    int t = threadIdx.x;
    int b = blockIdx.x;
    int j = b >> 4, kb = b & 15;
    int k0 = kb * 1024 + t * 4;
    float4 w = *(const float4*)(fc1w + (size_t)j * 16384 + k0);
    float we[4] = {w.x, w.y, w.z, w.w};
    int out[4] = {0, 0, 0, 0};
    #pragma unroll
    for (int e = 0; e < 4; e++) {
        int q = (int)rint((double)we[e] * 4294967296.0);
        q = min(max(q, -266338304), 266338304);
        int d0 = ((q + 64) & 127) - 64; q = (q - d0) >> 7;
        int d1 = ((q + 64) & 127) - 64; q = (q - d1) >> 7;
        int d2 = ((q + 64) & 127) - 64; q = (q - d2) >> 7;
        int d3 = q;
        out[0] |= (d0 & 0xff) << (8 * e);
        out[1] |= (d1 & 0xff) << (8 * e);
        out[2] |= (d2 & 0xff) << (8 * e);
        out[3] |= (d3 & 0xff) << (8 * e);
    }
    #pragma unroll
    for (int m = 0; m < 4; m++)
        *(int*)(BL + (size_t)(j * 4 + m) * 16384 + k0) = out[m];
}

// -------- Kernel 4a: fc1 GEMM. R14 geometry:
// block 128n x 256jm, 8 waves = 2n x 2j x 2 K-phase, wave tile 64n x 128jm,
// K-step 128 (phase waves split the 128B row 64B/64B), dbuf 96 KiB, 1 blk/CU.
// Per CU-iter: LDS 144KB=1125cyc < MFMA 256x5.1=1306cyc -> MFMA-bound.
__global__ __launch_bounds__(512, 2) void k4a_fc1(
    const signed char* __restrict__ hT2, const signed char* __restrict__ BL,
    double* __restrict__ Pd)
{
    __shared__ __align__(16) signed char smem[98304];  // 2 x (A 16K + B 32K)
    int t = threadIdx.x, l = t & 63, wid = t >> 6;
    int nb0 = blockIdx.y * 128, jb0 = blockIdx.x * 256;
    int kh = blockIdx.z, k0 = kh * 8192;
    int ksw = wid >> 2;                                   // K-phase
    int wn0 = ((wid >> 1) & 1) * 64, wj0 = (wid & 1) * 128;

    int srow = l >> 3;
    int sseg = ((l & 7) ^ srow) * 16;                     // pre-swizzled source
    const signed char* gA = hT2 + (size_t)(nb0 + wid * 16 + srow) * 16384 + k0 + sseg;
    const signed char* gB = BL  + (size_t)(jb0 + wid * 32 + srow) * 16384 + k0 + sseg;

    v4i acc[4][8];
    #pragma unroll
    for (int i = 0; i < 4; i++)
        #pragma unroll
        for (int q = 0; q < 8; q++) acc[i][q] = (v4i){0, 0, 0, 0};

    {   // prologue: stage K-slot 0 into buf0
        signed char* As = smem;
        signed char* Bs = smem + 16384;
        #pragma unroll
        for (int c = 0; c < 2; c++)
            async16(gA + (size_t)c * 8 * 16384, As + (wid * 16 + c * 8) * 128);
        #pragma unroll
        for (int c = 0; c < 4; c++)
            async16(gB + (size_t)c * 8 * 16384, Bs + (wid * 32 + c * 8) * 128);
    }

    int sw = (((ksw * 4) + (l >> 4)) ^ (l & 7)) * 16;     // read swizzle (key l&7 == row&7)

    for (int it = 0; it < 64; it++) {
        __syncthreads();
        if (it + 1 < 64) {
            int kt = (it + 1) * 128;
            signed char* As = smem + ((it + 1) & 1) * 49152;
            signed char* Bs = As + 16384;
            #pragma unroll
            for (int c = 0; c < 2; c++)
                async16(gA + (size_t)c * 8 * 16384 + kt, As + (wid * 16 + c * 8) * 128);
            #pragma unroll
            for (int c = 0; c < 4; c++)
                async16(gB + (size_t)c * 8 * 16384 + kt, Bs + (wid * 32 + c * 8) * 128);
        }
        const signed char* As = smem + (it & 1) * 49152;
        const signed char* Bs = As + 16384;
        v4i af[4], bf[8];
        #pragma unroll
        for (int i = 0; i < 4; i++)
            af[i] = *(const v4i*)&As[(wn0 + i * 16 + (l & 15)) * 128 + sw];
        #pragma unroll
        for (int q = 0; q < 8; q++)
            bf[q] = *(const v4i*)&Bs[(wj0 + q * 16 + (l & 15)) * 128 + sw];
        #pragma unroll
        for (int i = 0; i < 4; i++)
            #pragma unroll
            for (int q = 0; q < 8; q++)
                acc[i][q] = __builtin_amdgcn_mfma_i32_16x16x64_i8(af[i], bf[q], acc[i][q], 0, 0, 0);
    }

    // Epilogue: combine K-phase wave pairs through 64 KB S, two 64n halves.
    __syncthreads();
    int* S = (int*)smem;                                  // [64 n][256 jm]
    #pragma unroll
    for (int h = 0; h < 2; h++) {
        if (h) __syncthreads();
        if (ksw == 0 && wn0 == h * 64) {
            #pragma unroll
            for (int i = 0; i < 4; i++)
                #pragma unroll
                for (int q = 0; q < 8; q++)
                    #pragma unroll
                    for (int rr = 0; rr < 4; rr++)
                        S[(i * 16 + (l >> 4) * 4 + rr) * 256 + (wj0 + q * 16 + (l & 15))]
                            = acc[i][q][rr];
        }
        __syncthreads();
        if (ksw == 1 && wn0 == h * 64) {
            #pragma unroll
            for (int i = 0; i < 4; i++)
                #pragma unroll
                for (int q = 0; q < 8; q++)
                    #pragma unroll
                    for (int rr = 0; rr < 4; rr++)
                        S[(i * 16 + (l >> 4) * 4 + rr) * 256 + (wj0 + q * 16 + (l & 15))]
                            += acc[i][q][rr];
        }
        __syncthreads();
        #pragma unroll
        for (int e = 0; e < 8; e++) {
            int idx = t * 8 + e;                          // 4096 = 64 n x 64 j
            int n_l = idx >> 6, j_l = idx & 63;
            int4 s = *(const int4*)&S[n_l * 256 + j_l * 4];
            double val = (double)s.x + 128.0 * (double)s.y
                       + 16384.0 * (double)s.z + 2097152.0 * (double)s.w;
            Pd[(size_t)kh * 1048576 + (size_t)(nb0 + h * 64 + n_l) * 1024
               + blockIdx.x * 64 + j_l] = val;
        }
    }
}

// -------- Kernel 45: combine K-halves + bias + sign, then fc2 (block per n).
__global__ __launch_bounds__(256) void k45_comb_fc2(
    const double* __restrict__ Pd, const float* __restrict__ fc1b,
    const float* __restrict__ fc2w, const float* __restrict__ fc2b,
    float* __restrict__ out)
{
    __shared__ double sj[1024];
    __shared__ double pw[4][10];
    int t = threadIdx.x, n = blockIdx.x;
    const double SCALE = 1.0 / 4294967296.0;

    #pragma unroll
    for (int rep = 0; rep < 4; rep++) {
        int j = rep * 256 + t;
        double v = Pd[(size_t)n * 1024 + j] + Pd[1048576 + (size_t)n * 1024 + j];
        double p = v * SCALE + (double)fc1b[j];
        sj[j] = (double)((p > 0.0) - (p < 0.0));
    }
    __syncthreads();

    int j0 = t * 4;
    double s0 = sj[j0], s1 = sj[j0 + 1], s2 = sj[j0 + 2], s3 = sj[j0 + 3];
    double acc[10];
    #pragma unroll
    for (int m = 0; m < 10; m++) {
        float4 w = *(const float4*)(fc2w + (size_t)m * 1024 + j0);
        acc[m] = s0 * (double)w.x + s1 * (double)w.y + s2 * (double)w.z + s3 * (double)w.w;
    }
    #pragma unroll
    for (int off = 32; off > 0; off >>= 1)
        #pragma unroll
        for (int m = 0; m < 10; m++)
            acc[m] += __shfl_down(acc[m], off);
    if ((t & 63) == 0)
        #pragma unroll
        for (int m = 0; m < 10; m++) pw[t >> 6][m] = acc[m];
    __syncthreads();
    if (t < 10)
        out[n * 10 + t] = (float)(pw[0][t] + pw[1][t] + pw[2][t] + pw[3][t] + (double)fc2b[t]);
}

// -------- Fallback (ws too small): R7-style combined k4 + old k5 via hs.
__global__ __launch_bounds__(512) void k4_fc1_mfma(
    const signed char* __restrict__ hT2, const signed char* __restrict__ BL,
    const float* __restrict__ fc1b, signed char* __restrict__ hs)
{
    __shared__ __align__(16) signed char smem[65536];
    int t = threadIdx.x, l = t & 63, wid = t >> 6;
    int nb0 = blockIdx.y * 128, jb0 = blockIdx.x * 128;
    int wn0 = (wid >> 1) * 32;
    int wj0 = (wid & 1) * 64;

    int srow = l >> 3;
    int sseg = ((l & 7) ^ srow) * 16;
    const signed char* gA = hT2 + (size_t)(nb0 + wid * 16 + srow) * 16384 + sseg;
    const signed char* gB = BL  + (size_t)(jb0 + wid * 16 + srow) * 16384 + sseg;

    v4i acc[2][4];
    #pragma unroll
    for (int i = 0; i < 2; i++)
        #pragma unroll
        for (int q = 0; q < 4; q++) acc[i][q] = (v4i){0, 0, 0, 0};

    {
        signed char* As = smem;
        signed char* Bs = smem + 16384;
        #pragma unroll
        for (int i = 0; i < 2; i++) {
            async16(gA + (size_t)i * 8 * 16384, As + (wid * 16 + i * 8) * 128);
            async16(gB + (size_t)i * 8 * 16384, Bs + (wid * 16 + i * 8) * 128);
        }
    }

    for (int it = 0; it < 128; it++) {
        __syncthreads();
        if (it + 1 < 128) {
            int kt = (it + 1) * 128;
            signed char* As = smem + ((it + 1) & 1) * 32768;
            signed char* Bs = As + 16384;
            #pragma unroll
            for (int i = 0; i < 2; i++) {
                async16(gA + (size_t)i * 8 * 16384 + kt, As + (wid * 16 + i * 8) * 128);
                async16(gB + (size_t)i * 8 * 16384 + kt, Bs + (wid * 16 + i * 8) * 128);
            }
        }
        const signed char* As = smem + (it & 1) * 32768;
        const signed char* Bs = As + 16384;
        #pragma unroll
        for (int ks = 0; ks < 2; ks++) {
            int sw = (((ks * 4) + (l >> 4)) ^ (l & 7)) * 16;
            v4i af[2], bf[4];
            #pragma unroll
            for (int i = 0; i < 2; i++)
                af[i] = *(const v4i*)&As[(wn0 + i * 16 + (l & 15)) * 128 + sw];
            #pragma unroll
            for (int q = 0; q < 4; q++)
                bf[q] = *(const v4i*)&Bs[(wj0 + q * 16 + (l & 15)) * 128 + sw];
            #pragma unroll
            for (int i = 0; i < 2; i++)
                #pragma unroll
                for (int q = 0; q < 4; q++)
                    acc[i][q] = __builtin_amdgcn_mfma_i32_16x16x64_i8(af[i], bf[q], acc[i][q], 0, 0, 0);
        }
    }

    __syncthreads();
    int* S = (int*)smem;
    #pragma unroll
    for (int i = 0; i < 2; i++)
        #pragma unroll
        for (int q = 0; q < 4; q++)
            #pragma unroll
            for (int rr = 0; rr < 4; rr++) {
                int n_l  = wn0 + i * 16 + (l >> 4) * 4 + rr;
                int jm_l = wj0 + q * 16 + (l & 15);
                S[n_l * 128 + jm_l] = acc[i][q][rr];
            }
    __syncthreads();

    const double SCALE = 1.0 / 4294967296.0;
    #pragma unroll
    for (int i = 0; i < 8; i++) {
        int idx = t * 8 + i;
        int n_l = idx >> 5, j_l = idx & 31;
        int4 s = *(const int4*)&S[n_l * 128 + j_l * 4];
        double val = (double)s.x + 128.0 * (double)s.y
                   + 16384.0 * (double)s.z + 2097152.0 * (double)s.w;
        int j = blockIdx.x * 32 + j_l;
        double p = val * SCALE + (double)fc1b[j];
        hs[(size_t)(nb0 + n_l) * 1024 + j] = (signed char)((p > 0.0) - (p < 0.0));
    }
}

__global__ void k5_fc2(const signed char* __restrict__ hs,
                       const float* __restrict__ fc2w, const float* __restrict__ fc2b,
                       float* __restrict__ out)
{
    int idx = blockIdx.x * 64 + threadIdx.x;
    if (idx >= 10240) return;
    int n = idx / 10, m = idx - n * 10;
    const signed char* hr = hs + (size_t)n * 1024;
    const float* wr = fc2w + (size_t)m * 1024;
    double acc = (double)fc2b[m];
    for (int jb = 0; jb < 1024; jb += 16) {
        int4 hv = *(const int4*)(hr + jb);
        int wd[4] = {hv.x, hv.y, hv.z, hv.w};
        #pragma unroll
        for (int u = 0; u < 4; u++)
            #pragma unroll
            for (int e = 0; e < 4; e++)
                acc += (double)(signed char)(wd[u] >> (8 * e)) * (double)wr[jb + u * 4 + e];
    }
    out[idx] = (float)acc;
}

extern "C" void kernel_launch(void* const* d_in, const int* in_sizes, int n_in,
                              void* d_out, int out_size, void* d_ws, size_t ws_size,
                              hipStream_t stream)
{
    const float* x    = (const float*)d_in[0];
    const float* w1dw = (const float*)d_in[1];
    const float* b1dw = (const float*)d_in[2];
    const float* w1pw = (const float*)d_in[3];
    const float* b1pw = (const float*)d_in[4];
    const float* w2dw = (const float*)d_in[5];
    const float* b2dw = (const float*)d_in[6];
    const float* w2pw = (const float*)d_in[7];
    const float* b2pw = (const float*)d_in[8];
    const float* fc1w = (const float*)d_in[9];
    const float* fc1b = (const float*)d_in[10];
    const float* fc2w = (const float*)d_in[11];
    const float* fc2b = (const float*)d_in[12];
    float* out = (float*)d_out;

    // workspace:
    //   pooled1T @0        33.5MB  (dead after k3_fused)
    //   BL       @0        64MiB   (written by kprep after k3_fused)
    //   hT2      @64MiB    16MiB
    //   w2s/b2adj@80MiB    33KB    (dead after k3_fused)
    //   hs       @80MiB    1MiB    (fallback path only)
    //   Pd       @84934656 16MiB   fp64 K-split partials
    char* ws = (char*)d_ws;
    signed char* pooled1T = (signed char*)(ws);
    signed char* hT2      = (signed char*)(ws + 67108864);
    signed char* w2s      = (signed char*)(ws + 83886080);
    int*         b2adj    = (int*)(ws + 83886080 + 32768);
    signed char* BL       = (signed char*)(ws);
    signed char* hs       = (signed char*)(ws + 83886080);
    double*      Pd       = (double*)(ws + 84934656);
    bool split = ws_size >= (size_t)84934656 + 16777216;

    hipLaunchKernelGGL(k1_conv1,  dim3(1024),  dim3(256), 0, stream,
                       x, w1dw, b1dw, w1pw, b1pw, w2pw, b2pw, pooled1T, w2s, b2adj);
    hipLaunchKernelGGL(k3_fused,  dim3(1024),  dim3(256), 0, stream,
                       pooled1T, w2dw, b2dw, w2s, b2adj, hT2);
    hipLaunchKernelGGL(kprep,     dim3(16384), dim3(256), 0, stream,
                       fc1w, BL);
    if (split) {
        hipLaunchKernelGGL(k4a_fc1,      dim3(16, 8, 2), dim3(512), 0, stream,
                           hT2, BL, Pd);
        hipLaunchKernelGGL(k45_comb_fc2, dim3(1024),     dim3(256), 0, stream,
                           Pd, fc1b, fc2w, fc2b, out);
    } else {
        hipLaunchKernelGGL(k4_fc1_mfma, dim3(32, 8), dim3(512), 0, stream,
                           hT2, BL, fc1b, hs);
        hipLaunchKernelGGL(k5_fc2,      dim3(160),   dim3(64),  0, stream,
                           hs, fc2w, fc2b, out);
    }
}

// Round 7
// 324.635 us; speedup vs baseline: 1.0786x; 1.0065x over previous
//
#include <hip/hip_runtime.h>

// BinaryConnectNet forward.
// R16 == R15 resubmitted verbatim (R6 bench was an infra failure: container
// acquisition failed twice; kernel never executed).
// R15: k1 fused into k3 -> k13. conv1 (double-precision, thread t = pixel t)
// writes Ps rows directly in the swizzled layout (k1's Obuf formula == k3's
// Ps formula), eliminating the pooled1T HBM round-trip (67 MB) + one launch
// + k3's staging-read prologue. kprep2 standalone again (runs first).
// k4a keeps the R14 intensity geometry (verified: out of top-5, was 88+).
// NOTE (R5 lesson): per-dispatch FETCH/WRITE on this workload launders other
// kernels' L3 write-backs; don't read them as per-kernel traffic.
// Math exact; absmax must stay 0.0002441406.

__device__ __forceinline__ int fsign(float v)  { return (v > 0.f) - (v < 0.f); }
__device__ __forceinline__ int dsign(double v) { return (v > 0.0) - (v < 0.0); }

typedef int v4i __attribute__((ext_vector_type(4)));

__device__ __forceinline__ void async16(const signed char* g, signed char* l) {
    __builtin_amdgcn_global_load_lds(
        (const __attribute__((address_space(1))) void*)g,
        (__attribute__((address_space(3))) void*)l, 16, 0, 0);
}

// -------- Prep: conv2-pw sign matrix + adjusted bias b2adj[o] = sign(b)-32*rowsum.
__global__ void kprep2(const float* __restrict__ w2pw, const float* __restrict__ b2pw,
                       signed char* __restrict__ w2s, int* __restrict__ b2adj)
{
    int o = blockIdx.x * 64 + threadIdx.x;   // 256
    int rs = 0;
    for (int cq = 0; cq < 32; cq++) {
        float4 w = *(const float4*)(w2pw + (size_t)o * 128 + cq * 4);
        int s0 = fsign(w.x), s1 = fsign(w.y), s2 = fsign(w.z), s3 = fsign(w.w);
        rs += s0 + s1 + s2 + s3;
        int pk = (s0 & 0xff) | ((s1 & 0xff) << 8) | ((s2 & 0xff) << 16) | ((s3 & 0xff) << 24);
        *(int*)(w2s + (size_t)o * 128 + cq * 4) = pk;
    }
    b2adj[o] = fsign(b2pw[o]) - 32 * rs;
}

// -------- Kernel 13 (fused): conv1(dw+pw+sign+maxpool) -> Ps in LDS ->
// depthwise conv2 + pointwise MFMA GEMM + sign + maxpool -> hT2.
// Block n = image n, 256 threads, 4 blocks/CU (LDS 39168 B).
__global__ __launch_bounds__(256, 4) void k13_fused(
    const float* __restrict__ x,
    const float* __restrict__ w1dw, const float* __restrict__ b1dw,
    const float* __restrict__ w1pw, const float* __restrict__ b1pw,
    const float* __restrict__ w2dw, const float* __restrict__ b2dw,
    const signed char* __restrict__ w2s, const int* __restrict__ b2adj,
    signed char* __restrict__ hT2)
{
    __shared__ __align__(16) signed char Ps[32768];
    // Phase A (prep + dw conv): sw4[1152] + sdb2[128].
    // Phase B (oc loop, after the first post-MFMA barrier): Os[64*80].
    __shared__ __align__(16) signed char Uni[5120];
    __shared__ int sb2adj[256];
    __shared__ float sdw[27], sbdw[3];
    __shared__ unsigned char spidx[128];

    signed char* sw4  = Uni;
    signed char* sdb2 = Uni + 1152;
    signed char* Os   = Uni;

    int t = threadIdx.x, l = t & 63, wid = t >> 6;
    int n = blockIdx.x;

    // ---- Phase -1: stage all tables (w1 prep + w2 prep), one barrier.
    if (t < 27) sdw[t] = (float)fsign(w1dw[t]);
    if (t < 3)  sbdw[t] = (float)fsign(b1dw[t]);
    if (t < 128) {
        int b0 = w1pw[t * 3 + 0] > 0.f;
        int b1 = w1pw[t * 3 + 1] > 0.f;
        int b2 = w1pw[t * 3 + 2] > 0.f;
        int b3 = b1pw[t] > 0.f;
        spidx[t] = (unsigned char)(b0 | (b1 << 1) | (b2 << 2) | (b3 << 3));
    }
    for (int i = t; i < 1152; i += 256) {
        int c = i & 127, tap = i >> 7;
        sw4[tap * 128 + c] = (signed char)fsign(w2dw[c * 9 + tap]);
    }
    if (t < 128) sdb2[t] = (signed char)(fsign(b2dw[t]) + 1);
    sb2adj[t] = b2adj[t];
    __syncthreads();

    // ---- Phase 0: conv1 for pixel t (px=t&15, py=t>>4), write Ps row t
    // in the swizzled layout (identical bytes to old pooled1T path).
    {
        int px = t & 15, py = t >> 4;
        double h[3][4];
        const float* xb = x + (size_t)n * 3 * 1024;
        #pragma unroll
        for (int c = 0; c < 3; c++) {
            const float* xc = xb + c * 1024;
            #pragma unroll
            for (int dy = 0; dy < 2; dy++)
            #pragma unroll
            for (int dx = 0; dx < 2; dx++) {
                int y = 2 * py + dy, xx = 2 * px + dx;
                double acc = (double)sbdw[c];
                #pragma unroll
                for (int ky = 0; ky < 3; ky++) {
                    int yy = y + ky - 1;
                    if (yy < 0 || yy > 31) continue;
                    #pragma unroll
                    for (int kx = 0; kx < 3; kx++) {
                        int xxx = xx + kx - 1;
                        if (xxx < 0 || xxx > 31) continue;
                        acc += (double)sdw[c * 9 + ky * 3 + kx] * (double)xc[yy * 32 + xxx];
                    }
                }
                h[c][dy * 2 + dx] = acc;
            }
        }

        double tv[4][4];
        #pragma unroll
        for (int q = 0; q < 4; q++) {
            double u = h[0][q] + h[1][q];
            double v = h[0][q] - h[1][q];
            tv[0][q] = v - h[2][q];
            tv[1][q] = u - h[2][q];
            tv[2][q] = v + h[2][q];
            tv[3][q] = u + h[2][q];
        }
        int mpack = 0;
        #pragma unroll
        for (int bp = 0; bp < 4; bp++) {
            int mxP = -2, mnP = 2, mxM = -2, mnM = 2;
            #pragma unroll
            for (int q = 0; q < 4; q++) {
                int sP = dsign(tv[bp][q] + 1.0);
                int sM = dsign(tv[bp][q] - 1.0);
                mxP = max(mxP, sP); mnP = min(mnP, sP);
                mxM = max(mxM, sM); mnM = min(mnM, sM);
            }
            int pat1 = 1 | (bp << 1);
            int pat0 = (~pat1) & 7;
            mpack |= (mxP + 1)   << (2 * (pat1 | 8));
            mpack |= (mxM + 1)   << (2 * pat1);
            mpack |= ((-mnM) + 1) << (2 * (pat0 | 8));
            mpack |= ((-mnP) + 1) << (2 * pat0);
        }

        signed char* prow = Ps + t * 128;
        const int* pint = (const int*)spidx;
        for (int ob = 0; ob < 32; ob++) {
            int pw = pint[ob];
            int cur = 0;
            #pragma unroll
            for (int e = 0; e < 4; e++) {
                int pi = (pw >> (8 * e)) & 15;
                int mv = ((mpack >> (pi * 2)) & 3) - 1;
                cur |= (mv & 0xff) << (8 * e);
            }
            int ad = (((ob >> 2) ^ (t & 7)) << 4) + (ob & 3) * 4;
            *(int*)(prow + ad) = cur;
        }
    }
    __syncthreads();

    // ---- Phase 1: depthwise conv2 (from Ps) -> af fragments.
    int frow = l & 15;

    v4i af[4][2];
    #pragma unroll
    for (int ks = 0; ks < 2; ks++) {
        int c0 = ks * 64 + (l >> 4) * 16;
        int cc = c0 >> 4;
        int4 w4[9];
        #pragma unroll
        for (int tap = 0; tap < 9; tap++)
            w4[tap] = *(const int4*)&sw4[tap * 128 + c0];
        int4 sdbv = *(const int4*)&sdb2[c0];

        #pragma unroll
        for (int i = 0; i < 4; i++) {
            int r = (wid * 4 + i) * 16 + frow;
            int py = r >> 5, px2 = (r >> 2) & 7, dy = (r >> 1) & 1, dx = r & 1;
            int y = 2 * py + dy, xq = 2 * px2 + dx;
            int4 cnt = (int4){0, 0, 0, 0};
            #pragma unroll
            for (int ky = 0; ky < 3; ky++) {
                int yy = y + ky - 1;
                int yc = min(max(yy, 0), 15);
                #pragma unroll
                for (int kx = 0; kx < 3; kx++) {
                    int xx2 = xq + kx - 1;
                    int xc = min(max(xx2, 0), 15);
                    int inb = ((yy == yc) && (xx2 == xc)) ? 0x01010101 : 0;
                    int p = yc * 16 + xc;
                    int4 v = *(const int4*)&Ps[p * 128 + ((cc ^ (p & 7)) * 16)];
                    int4 w = w4[ky * 3 + kx];
                    cnt.x += ((v.x ^ w.x) >> 1) & inb;
                    cnt.y += ((v.y ^ w.y) >> 1) & inb;
                    cnt.z += ((v.z ^ w.z) >> 1) & inb;
                    cnt.w += ((v.w ^ w.w) >> 1) & inb;
                }
            }
            int valid = (1 + (y > 0) + (y < 15)) * (1 + (xq > 0) + (xq < 15));
            int mb = (valid + 31) * 0x01010101;
            int4 u;
            u.x = sdbv.x + mb - (cnt.x + cnt.x);
            u.y = sdbv.y + mb - (cnt.y + cnt.y);
            u.z = sdbv.z + mb - (cnt.z + cnt.z);
            u.w = sdbv.w + mb - (cnt.w + cnt.w);
            af[i][ks] = (v4i){u.x, u.y, u.z, u.w};
        }
    }

    // ---- Phase 2: pointwise GEMM + sign + maxpool epilogue.
    for (int oc = 0; oc < 4; oc++) {
        v4i acc[4][4];
        #pragma unroll
        for (int i = 0; i < 4; i++)
            #pragma unroll
            for (int jt = 0; jt < 4; jt++) acc[i][jt] = (v4i){0, 0, 0, 0};

        #pragma unroll
        for (int ks = 0; ks < 2; ks++) {
            v4i bf[4];
            #pragma unroll
            for (int jt = 0; jt < 4; jt++)
                bf[jt] = *(const v4i*)(w2s + (size_t)(oc * 64 + jt * 16 + frow) * 128
                                       + ks * 64 + (l >> 4) * 16);
            __builtin_amdgcn_s_setprio(1);
            #pragma unroll
            for (int i = 0; i < 4; i++)
                #pragma unroll
                for (int jt = 0; jt < 4; jt++)
                    acc[i][jt] = __builtin_amdgcn_mfma_i32_16x16x64_i8(af[i][ks], bf[jt], acc[i][jt], 0, 0, 0);
            __builtin_amdgcn_s_setprio(0);
        }

        __syncthreads();
        // From here Uni is the Os staging buffer (sw4/sdb2/spidx dead).
        #pragma unroll
        for (int jt = 0; jt < 4; jt++) {
            int o_l = jt * 16 + frow;
            int bia = sb2adj[oc * 64 + o_l];
            #pragma unroll
            for (int i = 0; i < 4; i++) {
                int mx = -2;
                #pragma unroll
                for (int rr = 0; rr < 4; rr++) {
                    int p = acc[i][jt][rr] + bia;
                    int s = (p > 0) - (p < 0);
                    mx = s > mx ? s : mx;
                }
                int pp = (wid * 4 + i) * 4 + (l >> 4);
                Os[o_l * 80 + pp] = (signed char)mx;
            }
        }
        __syncthreads();
        *(int4*)&hT2[(size_t)n * 16384 + oc * 4096 + t * 16]
            = *(const int4*)&Os[(t >> 2) * 80 + (t & 3) * 16];
    }
}

// -------- Prep: fc1_w -> 4 signed radix-128 int8 limbs on 2^-32 grid (exact).
__global__ void kprep(const float* __restrict__ fc1w, signed char* __restrict__ BL)
{
    int t = threadIdx.x;
    int b = blockIdx.x;
    int j = b >> 4, kb = b & 15;
    int k0 = kb * 1024 + t * 4;
    float4 w = *(const float4*)(fc1w + (size_t)j * 16384 + k0);
    float we[4] = {w.x, w.y, w.z, w.w};
    int out[4] = {0, 0, 0, 0};
    #pragma unroll
    for (int e = 0; e < 4; e++) {
        int q = (int)rint((double)we[e] * 4294967296.0);
        q = min(max(q, -266338304), 266338304);
        int d0 = ((q + 64) & 127) - 64; q = (q - d0) >> 7;
        int d1 = ((q + 64) & 127) - 64; q = (q - d1) >> 7;
        int d2 = ((q + 64) & 127) - 64; q = (q - d2) >> 7;
        int d3 = q;
        out[0] |= (d0 & 0xff) << (8 * e);
        out[1] |= (d1 & 0xff) << (8 * e);
        out[2] |= (d2 & 0xff) << (8 * e);
        out[3] |= (d3 & 0xff) << (8 * e);
    }
    #pragma unroll
    for (int m = 0; m < 4; m++)
        *(int*)(BL + (size_t)(j * 4 + m) * 16384 + k0) = out[m];
}

// -------- Kernel 4a: fc1 GEMM (R14 geometry, verified):
// block 128n x 256jm, 8 waves = 2n x 2j x 2 K-phase, wave tile 64n x 128jm,
// K-step 128, dbuf 96 KiB, 1 blk/CU, grid 16x8x2.
__global__ __launch_bounds__(512, 2) void k4a_fc1(
    const signed char* __restrict__ hT2, const signed char* __restrict__ BL,
    double* __restrict__ Pd)
{
    __shared__ __align__(16) signed char smem[98304];  // 2 x (A 16K + B 32K)
    int t = threadIdx.x, l = t & 63, wid = t >> 6;
    int nb0 = blockIdx.y * 128, jb0 = blockIdx.x * 256;
    int kh = blockIdx.z, k0 = kh * 8192;
    int ksw = wid >> 2;                                   // K-phase
    int wn0 = ((wid >> 1) & 1) * 64, wj0 = (wid & 1) * 128;

    int srow = l >> 3;
    int sseg = ((l & 7) ^ srow) * 16;                     // pre-swizzled source
    const signed char* gA = hT2 + (size_t)(nb0 + wid * 16 + srow) * 16384 + k0 + sseg;
    const signed char* gB = BL  + (size_t)(jb0 + wid * 32 + srow) * 16384 + k0 + sseg;

    v4i acc[4][8];
    #pragma unroll
    for (int i = 0; i < 4; i++)
        #pragma unroll
        for (int q = 0; q < 8; q++) acc[i][q] = (v4i){0, 0, 0, 0};

    {   // prologue: stage K-slot 0 into buf0
        signed char* As = smem;
        signed char* Bs = smem + 16384;
        #pragma unroll
        for (int c = 0; c < 2; c++)
            async16(gA + (size_t)c * 8 * 16384, As + (wid * 16 + c * 8) * 128);
        #pragma unroll
        for (int c = 0; c < 4; c++)
            async16(gB + (size_t)c * 8 * 16384, Bs + (wid * 32 + c * 8) * 128);
    }

    int sw = (((ksw * 4) + (l >> 4)) ^ (l & 7)) * 16;     // read swizzle

    for (int it = 0; it < 64; it++) {
        __syncthreads();
        if (it + 1 < 64) {
            int kt = (it + 1) * 128;
            signed char* As = smem + ((it + 1) & 1) * 49152;
            signed char* Bs = As + 16384;
            #pragma unroll
            for (int c = 0; c < 2; c++)
                async16(gA + (size_t)c * 8 * 16384 + kt, As + (wid * 16 + c * 8) * 128);
            #pragma unroll
            for (int c = 0; c < 4; c++)
                async16(gB + (size_t)c * 8 * 16384 + kt, Bs + (wid * 32 + c * 8) * 128);
        }
        const signed char* As = smem + (it & 1) * 49152;
        const signed char* Bs = As + 16384;
        v4i af[4], bf[8];
        #pragma unroll
        for (int i = 0; i < 4; i++)
            af[i] = *(const v4i*)&As[(wn0 + i * 16 + (l & 15)) * 128 + sw];
        #pragma unroll
        for (int q = 0; q < 8; q++)
            bf[q] = *(const v4i*)&Bs[(wj0 + q * 16 + (l & 15)) * 128 + sw];
        #pragma unroll
        for (int i = 0; i < 4; i++)
            #pragma unroll
            for (int q = 0; q < 8; q++)
                acc[i][q] = __builtin_amdgcn_mfma_i32_16x16x64_i8(af[i], bf[q], acc[i][q], 0, 0, 0);
    }

    // Epilogue: combine K-phase wave pairs through 64 KB S, two 64n halves.
    __syncthreads();
    int* S = (int*)smem;                                  // [64 n][256 jm]
    #pragma unroll
    for (int h = 0; h < 2; h++) {
        if (h) __syncthreads();
        if (ksw == 0 && wn0 == h * 64) {
            #pragma unroll
            for (int i = 0; i < 4; i++)
                #pragma unroll
                for (int q = 0; q < 8; q++)
                    #pragma unroll
                    for (int rr = 0; rr < 4; rr++)
                        S[(i * 16 + (l >> 4) * 4 + rr) * 256 + (wj0 + q * 16 + (l & 15))]
                            = acc[i][q][rr];
        }
        __syncthreads();
        if (ksw == 1 && wn0 == h * 64) {
            #pragma unroll
            for (int i = 0; i < 4; i++)
                #pragma unroll
                for (int q = 0; q < 8; q++)
                    #pragma unroll
                    for (int rr = 0; rr < 4; rr++)
                        S[(i * 16 + (l >> 4) * 4 + rr) * 256 + (wj0 + q * 16 + (l & 15))]
                            += acc[i][q][rr];
        }
        __syncthreads();
        #pragma unroll
        for (int e = 0; e < 8; e++) {
            int idx = t * 8 + e;                          // 4096 = 64 n x 64 j
            int n_l = idx >> 6, j_l = idx & 63;
            int4 s = *(const int4*)&S[n_l * 256 + j_l * 4];
            double val = (double)s.x + 128.0 * (double)s.y
                       + 16384.0 * (double)s.z + 2097152.0 * (double)s.w;
            Pd[(size_t)kh * 1048576 + (size_t)(nb0 + h * 64 + n_l) * 1024
               + blockIdx.x * 64 + j_l] = val;
        }
    }
}

// -------- Kernel 45: combine K-halves + bias + sign, then fc2 (block per n).
__global__ __launch_bounds__(256) void k45_comb_fc2(
    const double* __restrict__ Pd, const float* __restrict__ fc1b,
    const float* __restrict__ fc2w, const float* __restrict__ fc2b,
    float* __restrict__ out)
{
    __shared__ double sj[1024];
    __shared__ double pw[4][10];
    int t = threadIdx.x, n = blockIdx.x;
    const double SCALE = 1.0 / 4294967296.0;

    #pragma unroll
    for (int rep = 0; rep < 4; rep++) {
        int j = rep * 256 + t;
        double v = Pd[(size_t)n * 1024 + j] + Pd[1048576 + (size_t)n * 1024 + j];
        double p = v * SCALE + (double)fc1b[j];
        sj[j] = (double)((p > 0.0) - (p < 0.0));
    }
    __syncthreads();

    int j0 = t * 4;
    double s0 = sj[j0], s1 = sj[j0 + 1], s2 = sj[j0 + 2], s3 = sj[j0 + 3];
    double acc[10];
    #pragma unroll
    for (int m = 0; m < 10; m++) {
        float4 w = *(const float4*)(fc2w + (size_t)m * 1024 + j0);
        acc[m] = s0 * (double)w.x + s1 * (double)w.y + s2 * (double)w.z + s3 * (double)w.w;
    }
    #pragma unroll
    for (int off = 32; off > 0; off >>= 1)
        #pragma unroll
        for (int m = 0; m < 10; m++)
            acc[m] += __shfl_down(acc[m], off);
    if ((t & 63) == 0)
        #pragma unroll
        for (int m = 0; m < 10; m++) pw[t >> 6][m] = acc[m];
    __syncthreads();
    if (t < 10)
        out[n * 10 + t] = (float)(pw[0][t] + pw[1][t] + pw[2][t] + pw[3][t] + (double)fc2b[t]);
}

// -------- Fallback (ws too small): R7-style combined k4 + old k5 via hs.
__global__ __launch_bounds__(512) void k4_fc1_mfma(
    const signed char* __restrict__ hT2, const signed char* __restrict__ BL,
    const float* __restrict__ fc1b, signed char* __restrict__ hs)
{
    __shared__ __align__(16) signed char smem[65536];
    int t = threadIdx.x, l = t & 63, wid = t >> 6;
    int nb0 = blockIdx.y * 128, jb0 = blockIdx.x * 128;
    int wn0 = (wid >> 1) * 32;
    int wj0 = (wid & 1) * 64;

    int srow = l >> 3;
    int sseg = ((l & 7) ^ srow) * 16;
    const signed char* gA = hT2 + (size_t)(nb0 + wid * 16 + srow) * 16384 + sseg;
    const signed char* gB = BL  + (size_t)(jb0 + wid * 16 + srow) * 16384 + sseg;

    v4i acc[2][4];
    #pragma unroll
    for (int i = 0; i < 2; i++)
        #pragma unroll
        for (int q = 0; q < 4; q++) acc[i][q] = (v4i){0, 0, 0, 0};

    {
        signed char* As = smem;
        signed char* Bs = smem + 16384;
        #pragma unroll
        for (int i = 0; i < 2; i++) {
            async16(gA + (size_t)i * 8 * 16384, As + (wid * 16 + i * 8) * 128);
            async16(gB + (size_t)i * 8 * 16384, Bs + (wid * 16 + i * 8) * 128);
        }
    }

    for (int it = 0; it < 128; it++) {
        __syncthreads();
        if (it + 1 < 128) {
            int kt = (it + 1) * 128;
            signed char* As = smem + ((it + 1) & 1) * 32768;
            signed char* Bs = As + 16384;
            #pragma unroll
            for (int i = 0; i < 2; i++) {
                async16(gA + (size_t)i * 8 * 16384 + kt, As + (wid * 16 + i * 8) * 128);
                async16(gB + (size_t)i * 8 * 16384 + kt, Bs + (wid * 16 + i * 8) * 128);
            }
        }
        const signed char* As = smem + (it & 1) * 32768;
        const signed char* Bs = As + 16384;
        #pragma unroll
        for (int ks = 0; ks < 2; ks++) {
            int sw = (((ks * 4) + (l >> 4)) ^ (l & 7)) * 16;
            v4i af[2], bf[4];
            #pragma unroll
            for (int i = 0; i < 2; i++)
                af[i] = *(const v4i*)&As[(wn0 + i * 16 + (l & 15)) * 128 + sw];
            #pragma unroll
            for (int q = 0; q < 4; q++)
                bf[q] = *(const v4i*)&Bs[(wj0 + q * 16 + (l & 15)) * 128 + sw];
            #pragma unroll
            for (int i = 0; i < 2; i++)
                #pragma unroll
                for (int q = 0; q < 4; q++)
                    acc[i][q] = __builtin_amdgcn_mfma_i32_16x16x64_i8(af[i], bf[q], acc[i][q], 0, 0, 0);
        }
    }

    __syncthreads();
    int* S = (int*)smem;
    #pragma unroll
    for (int i = 0; i < 2; i++)
        #pragma unroll
        for (int q = 0; q < 4; q++)
            #pragma unroll
            for (int rr = 0; rr < 4; rr++) {
                int n_l  = wn0 + i * 16 + (l >> 4) * 4 + rr;
                int jm_l = wj0 + q * 16 + (l & 15);
                S[n_l * 128 + jm_l] = acc[i][q][rr];
            }
    __syncthreads();

    const double SCALE = 1.0 / 4294967296.0;
    #pragma unroll
    for (int i = 0; i < 8; i++) {
        int idx = t * 8 + i;
        int n_l = idx >> 5, j_l = idx & 31;
        int4 s = *(const int4*)&S[n_l * 128 + j_l * 4];
        double val = (double)s.x + 128.0 * (double)s.y
                   + 16384.0 * (double)s.z + 2097152.0 * (double)s.w;
        int j = blockIdx.x * 32 + j_l;
        double p = val * SCALE + (double)fc1b[j];
        hs[(size_t)(nb0 + n_l) * 1024 + j] = (signed char)((p > 0.0) - (p < 0.0));
    }
}

__global__ void k5_fc2(const signed char* __restrict__ hs,
                       const float* __restrict__ fc2w, const float* __restrict__ fc2b,
                       float* __restrict__ out)
{
    int idx = blockIdx.x * 64 + threadIdx.x;
    if (idx >= 10240) return;
    int n = idx / 10, m = idx - n * 10;
    const signed char* hr = hs + (size_t)n * 1024;
    const float* wr = fc2w + (size_t)m * 1024;
    double acc = (double)fc2b[m];
    for (int jb = 0; jb < 1024; jb += 16) {
        int4 hv = *(const int4*)(hr + jb);
        int wd[4] = {hv.x, hv.y, hv.z, hv.w};
        #pragma unroll
        for (int u = 0; u < 4; u++)
            #pragma unroll
            for (int e = 0; e < 4; e++)
                acc += (double)(signed char)(wd[u] >> (8 * e)) * (double)wr[jb + u * 4 + e];
    }
    out[idx] = (float)acc;
}

extern "C" void kernel_launch(void* const* d_in, const int* in_sizes, int n_in,
                              void* d_out, int out_size, void* d_ws, size_t ws_size,
                              hipStream_t stream)
{
    const float* x    = (const float*)d_in[0];
    const float* w1dw = (const float*)d_in[1];
    const float* b1dw = (const float*)d_in[2];
    const float* w1pw = (const float*)d_in[3];
    const float* b1pw = (const float*)d_in[4];
    const float* w2dw = (const float*)d_in[5];
    const float* b2dw = (const float*)d_in[6];
    const float* w2pw = (const float*)d_in[7];
    const float* b2pw = (const float*)d_in[8];
    const float* fc1w = (const float*)d_in[9];
    const float* fc1b = (const float*)d_in[10];
    const float* fc2w = (const float*)d_in[11];
    const float* fc2b = (const float*)d_in[12];
    float* out = (float*)d_out;

    // workspace:
    //   BL       @0        64MiB   (written by kprep after k13)
    //   hT2      @64MiB    16MiB
    //   w2s/b2adj@80MiB    33KB    (written by kprep2, read by k13)
    //   hs       @80MiB+1M 1MiB    (fallback path only; after w2s is dead)
    //   Pd       @84934656 16MiB   fp64 K-split partials
    char* ws = (char*)d_ws;
    signed char* hT2      = (signed char*)(ws + 67108864);
    signed char* w2s      = (signed char*)(ws + 83886080);
    int*         b2adj    = (int*)(ws + 83886080 + 32768);
    signed char* BL       = (signed char*)(ws);
    signed char* hs       = (signed char*)(ws + 83886080 + 1048576);
    double*      Pd       = (double*)(ws + 84934656);
    bool split = ws_size >= (size_t)84934656 + 16777216;

    hipLaunchKernelGGL(kprep2,    dim3(4),     dim3(64),  0, stream,
                       w2pw, b2pw, w2s, b2adj);
    hipLaunchKernelGGL(k13_fused, dim3(1024),  dim3(256), 0, stream,
                       x, w1dw, b1dw, w1pw, b1pw, w2dw, b2dw, w2s, b2adj, hT2);
    hipLaunchKernelGGL(kprep,     dim3(16384), dim3(256), 0, stream,
                       fc1w, BL);
    if (split) {
        hipLaunchKernelGGL(k4a_fc1,      dim3(16, 8, 2), dim3(512), 0, stream,
                           hT2, BL, Pd);
        hipLaunchKernelGGL(k45_comb_fc2, dim3(1024),     dim3(256), 0, stream,
                           Pd, fc1b, fc2w, fc2b, out);
    } else {
        hipLaunchKernelGGL(k4_fc1_mfma, dim3(32, 8), dim3(512), 0, stream,
                           hT2, BL, fc1b, hs);
        hipLaunchKernelGGL(k5_fc2,      dim3(160),   dim3(64),  0, stream,
                           hs, fc2w, fc2b, out);
    }
}